// Round 13
// baseline (2100.172 us; speedup 1.0000x reference)
//
#include <hip/hip_runtime.h>

// ---------------------------------------------------------------------------
// Transformer decoder fwd, bf16-MFMA compute, fp32 residual stream in d_out.
// L=8 B=4 S=1024 D=1024 H=16 dh=64 FC=4096. Threshold 0.1 allows bf16 GEMMs.
// QKV/W1: 256^2 ring GEMM (BK=32, 7-slot ring, counted vmcnt(4), swizzle
// slot^=(row>>1)&3). Wo/W2: proven gemm2 128x64 2-phase dbuf (2 blocks/CU).
// Attn v8: swapped QK^T + swapped PV (O^T, zero-LDS P exchange) + balanced
// in-block KV-split: block = q-tile pair (p, 63-p), each q-tile split across
// 2 waves (max chain 8 tiles), LDS merge. 2048 equal-work blocks.
// ---------------------------------------------------------------------------

typedef __bf16 bf16x8 __attribute__((ext_vector_type(8)));
typedef float  f32x4  __attribute__((ext_vector_type(4)));
typedef unsigned int u32x4 __attribute__((ext_vector_type(4)));

#define DEV static __device__ __forceinline__

DEV unsigned short f2bf(float x) {
  unsigned u = __builtin_bit_cast(unsigned int, x);
  u += 0x7fffu + ((u >> 16) & 1u);          // RNE
  return (unsigned short)(u >> 16);
}

DEV unsigned int pack2bf(float lo, float hi) {
  return (unsigned int)f2bf(lo) | ((unsigned int)f2bf(hi) << 16);
}

DEV f32x4 mfma16(bf16x8 a, bf16x8 b, f32x4 c) {
  return __builtin_amdgcn_mfma_f32_16x16x32_bf16(a, b, c, 0, 0, 0);
}

DEV bf16x8 ldb8(const unsigned short* p) {
  return *reinterpret_cast<const bf16x8*>(p);
}

DEV void gload_lds16(const unsigned short* g, unsigned short* l) {
  __builtin_amdgcn_global_load_lds(
      (const __attribute__((address_space(1))) void*)g,
      (__attribute__((address_space(3))) void*)l, 16, 0, 0);
}

// ---------------------------------------------------------------------------
// fp32 [K][N] -> bf16 [N][K] transposed convert (32x32 LDS tile)
// ---------------------------------------------------------------------------
__global__ void transpose_cvt(const float* __restrict__ src,
                              unsigned short* __restrict__ dst,
                              int srcStride, int dstStride) {
  __shared__ float tile[32][33];
  const int t  = threadIdx.x;
  const int r  = t >> 3;
  const int c4 = (t & 7) << 2;
  const int k  = blockIdx.x * 32 + r;
  const int n0 = blockIdx.y * 32 + c4;
  const float4 v = *reinterpret_cast<const float4*>(src + (size_t)k * srcStride + n0);
  tile[r][c4] = v.x; tile[r][c4 + 1] = v.y; tile[r][c4 + 2] = v.z; tile[r][c4 + 3] = v.w;
  __syncthreads();
  const int n  = blockIdx.y * 32 + r;
  const int k0 = blockIdx.x * 32 + c4;
  ushort4 o;
  o.x = f2bf(tile[c4][r]);     o.y = f2bf(tile[c4 + 1][r]);
  o.z = f2bf(tile[c4 + 2][r]); o.w = f2bf(tile[c4 + 3][r]);
  *reinterpret_cast<ushort4*>(dst + (size_t)n * dstStride + k0) = o;
}

// 4 x (1024x1024) transposes in one dispatch (z = which matrix)
__global__ void transpose_cvt4(const float* __restrict__ Wq, const float* __restrict__ Wk,
                               const float* __restrict__ Wv, const float* __restrict__ Wo,
                               unsigned short* __restrict__ Wqkv_t,
                               unsigned short* __restrict__ Wo_t) {
  __shared__ float tile[32][33];
  const int z = blockIdx.z;
  const float* src = (z == 0) ? Wq : (z == 1) ? Wk : (z == 2) ? Wv : Wo;
  unsigned short* dst = (z == 3) ? Wo_t : (Wqkv_t + (size_t)z * 1024 * 1024);
  const int t  = threadIdx.x;
  const int r  = t >> 3;
  const int c4 = (t & 7) << 2;
  const int k  = blockIdx.x * 32 + r;
  const int n0 = blockIdx.y * 32 + c4;
  const float4 v = *reinterpret_cast<const float4*>(src + (size_t)k * 1024 + n0);
  tile[r][c4] = v.x; tile[r][c4 + 1] = v.y; tile[r][c4 + 2] = v.z; tile[r][c4 + 3] = v.w;
  __syncthreads();
  const int n  = blockIdx.y * 32 + r;
  const int k0 = blockIdx.x * 32 + c4;
  ushort4 o;
  o.x = f2bf(tile[c4][r]);     o.y = f2bf(tile[c4 + 1][r]);
  o.z = f2bf(tile[c4 + 2][r]); o.w = f2bf(tile[c4 + 3][r]);
  *reinterpret_cast<ushort4*>(dst + (size_t)n * 1024 + k0) = o;
}

__global__ void pack_qkv_bias(const float* __restrict__ bq, const float* __restrict__ bk,
                              const float* __restrict__ bv, float* __restrict__ out) {
  int i = blockIdx.x * 256 + threadIdx.x;   // 3072
  out[i] = (i < 1024) ? bq[i] : (i < 2048 ? bk[i - 1024] : bv[i - 2048]);
}

// ---------------------------------------------------------------------------
// LayerNorm v2: ONE WAVE PER ROW (D=1024 -> 16 floats/lane), 4 rows/block,
// grid = 1024. Pure shfl_xor reduction, no LDS, no block barrier.
// ---------------------------------------------------------------------------
template <int OUTF32>
__global__ __launch_bounds__(256) void ln_kernel(
    const float* x, const float* __restrict__ gam,
    const float* __restrict__ bet, void* out) {
  const int t = threadIdx.x, wave = t >> 6, lane = t & 63;
  const int row = blockIdx.x * 4 + wave;
  const float* xr = x + (size_t)row * 1024;
  float4 v[4];
  float s = 0.f, ss = 0.f;
  #pragma unroll
  for (int k = 0; k < 4; ++k) {
    v[k] = *reinterpret_cast<const float4*>(xr + k * 256 + lane * 4);
    s  += v[k].x + v[k].y + v[k].z + v[k].w;
    ss += v[k].x * v[k].x + v[k].y * v[k].y + v[k].z * v[k].z + v[k].w * v[k].w;
  }
  #pragma unroll
  for (int m = 1; m <= 32; m <<= 1) { s += __shfl_xor(s, m); ss += __shfl_xor(ss, m); }
  const float mean = s * (1.0f / 1024.0f);
  const float var  = ss * (1.0f / 1024.0f) - mean * mean;
  const float rstd = rsqrtf(var + 1e-5f);
  #pragma unroll
  for (int k = 0; k < 4; ++k) {
    const float4 g  = *reinterpret_cast<const float4*>(gam + k * 256 + lane * 4);
    const float4 bb = *reinterpret_cast<const float4*>(bet + k * 256 + lane * 4);
    const float y0 = (v[k].x - mean) * rstd * g.x + bb.x;
    const float y1 = (v[k].y - mean) * rstd * g.y + bb.y;
    const float y2 = (v[k].z - mean) * rstd * g.z + bb.z;
    const float y3 = (v[k].w - mean) * rstd * g.w + bb.w;
    if (OUTF32) {
      float4 o; o.x = y0; o.y = y1; o.z = y2; o.w = y3;
      *reinterpret_cast<float4*>((float*)out + (size_t)row * 1024 + k * 256 + lane * 4) = o;
    } else {
      ushort4 o; o.x = f2bf(y0); o.y = f2bf(y1); o.z = f2bf(y2); o.w = f2bf(y3);
      *reinterpret_cast<ushort4*>((unsigned short*)out + (size_t)row * 1024 + k * 256 + lane * 4) = o;
    }
  }
}

// ---------------------------------------------------------------------------
// gemm8r: 256x256 tile, BK=32, 512 thr = 8 waves (2M x 4N, per-wave 128x64).
// 7-slot ring x 16KB; stage t+2; counted vmcnt(4); swizzle slot^=(row>>1)&3.
// MODE 1: bias+gelu->bf16. MODE 3: QKV split (V -> vT transposed).
// grid 1-D (XCD-swizzled, %8==0), block = 512
// ---------------------------------------------------------------------------
template <int MODE>
__global__ __launch_bounds__(512) void gemm8r(
    const unsigned short* __restrict__ A, const unsigned short* __restrict__ Bt,
    const float* __restrict__ bias, unsigned short* __restrict__ outb,
    unsigned short* __restrict__ vT, int N, int K) {
  __shared__ __attribute__((aligned(16))) unsigned short lds[7 * 8192]; // 112KB
  const int t = threadIdx.x, wave = t >> 6, lane = t & 63;
  const int wm = wave >> 2, wn = wave & 3;
  const int rl15 = lane & 15;

  const int nbn = N >> 8;
  const int qq  = gridDim.x >> 3;
  const int swz = (blockIdx.x & 7) * qq + (blockIdx.x >> 3);
  const int m0 = (swz / nbn) << 8, n0 = (swz % nbn) << 8;

  const unsigned short* aG = A  + (size_t)m0 * K;
  const unsigned short* bG = Bt + (size_t)n0 * K;

  const int srow = lane >> 2;
  const int ssl  = (((lane & 3) ^ ((srow >> 1) & 3)) << 3);   // shorts
  const int swA  = (((lane >> 4) ^ ((lane >> 1) & 3)) << 3);  // shorts

  auto stageA = [&](int slot, int kt) {
    #pragma unroll
    for (int j = 0; j < 2; ++j) {
      const int c = wave + j * 8;
      gload_lds16(aG + (size_t)(c * 16 + srow) * K + kt * 32 + ssl,
                  &lds[slot * 8192 + c * 512]);
    }
  };
  auto stageB = [&](int slot, int kt) {
    #pragma unroll
    for (int j = 0; j < 2; ++j) {
      const int c = wave + j * 8;
      gload_lds16(bG + (size_t)(c * 16 + srow) * K + kt * 32 + ssl,
                  &lds[slot * 8192 + c * 512]);
    }
  };

  const int nk = K >> 5;
  stageA(0, 0); stageB(1, 0);
  stageA(2, 1); stageB(3, 1);
  asm volatile("s_waitcnt vmcnt(4)" ::: "memory");
  asm volatile("s_barrier" ::: "memory");

  f32x4 acc[8][4] = {};
  int sA = 0, sB = 1, pA = 4, pB = 5;

  for (int kt = 0; kt < nk; ++kt) {
    const bool more = (kt + 2 < nk);
    if (more) { stageA(pA, kt + 2); stageB(pB, kt + 2); }
    const int ab = sA * 8192, bb = sB * 8192;
    bf16x8 af[8], bfr[4];
    #pragma unroll
    for (int mi = 0; mi < 8; ++mi)
      af[mi] = ldb8(&lds[ab + (wm * 128 + mi * 16 + rl15) * 32 + swA]);
    #pragma unroll
    for (int ni = 0; ni < 4; ++ni)
      bfr[ni] = ldb8(&lds[bb + (wn * 64 + ni * 16 + rl15) * 32 + swA]);
    __builtin_amdgcn_s_setprio(1);
    #pragma unroll
    for (int mi = 0; mi < 8; ++mi)
      #pragma unroll
      for (int ni = 0; ni < 4; ++ni)
        acc[mi][ni] = mfma16(af[mi], bfr[ni], acc[mi][ni]);
    __builtin_amdgcn_s_setprio(0);
    if (more) asm volatile("s_waitcnt vmcnt(4)" ::: "memory");
    else      asm volatile("s_waitcnt vmcnt(0)" ::: "memory");
    asm volatile("s_barrier" ::: "memory");
    sA += 2; if (sA >= 7) sA -= 7;
    sB += 2; if (sB >= 7) sB -= 7;
    pA += 2; if (pA >= 7) pA -= 7;
    pB += 2; if (pB >= 7) pB -= 7;
  }

  const int mrow = m0 + wm * 128 + (lane >> 4) * 4;
  const int ncol = n0 + wn * 64 + rl15;
  #pragma unroll
  for (int ni = 0; ni < 4; ++ni) {
    const int n = ncol + ni * 16;
    const float bn = bias[n];
    #pragma unroll
    for (int mi = 0; mi < 8; ++mi) {
      const int row0 = mrow + mi * 16;
      if constexpr (MODE == 3) {
        if (n >= 2048) {                               // V -> vT[b,h,d,s]
          const int h = (n - 2048) >> 6, d = (n - 2048) & 63;
          const int b = row0 >> 10, s = row0 & 1023;
          ushort4 o;
          o.x = f2bf(acc[mi][ni][0] + bn); o.y = f2bf(acc[mi][ni][1] + bn);
          o.z = f2bf(acc[mi][ni][2] + bn); o.w = f2bf(acc[mi][ni][3] + bn);
          *reinterpret_cast<ushort4*>(vT + ((size_t)(b * 16 + h) * 64 + d) * 1024 + s) = o;
          continue;
        }
      }
      #pragma unroll
      for (int r = 0; r < 4; ++r) {
        const size_t idx = (size_t)(row0 + r) * N + n;
        float v = acc[mi][ni][r] + bn;
        if constexpr (MODE == 1)
          v = 0.5f * v * (1.0f + erff(v * 0.70710678118f));  // exact GELU
        outb[idx] = f2bf(v);
      }
    }
  }
}

// ---------------------------------------------------------------------------
// GEMM v2 (proven, R8 config): 128 x BN tile, BK=64, 4 waves, dbuf LDS,
// XOR swizzle (chunk ^= row&7 on 128B rows). 2-phase pipeline.
// MODE 2: xout = xin + scl*(C+bias) (f32 residual). grid (M/128, N/BN).
// ---------------------------------------------------------------------------
template <int MODE, int BN>
__global__ __launch_bounds__(256) void gemm2(
    const unsigned short* __restrict__ A, const unsigned short* __restrict__ Bt,
    const float* __restrict__ bias, unsigned short* __restrict__ outb,
    const float* xin, float* xout, const float* __restrict__ scale_p,
    int N, int K) {
  constexpr int NI = BN / 32;
  constexpr int BSH = BN * 64;
  __shared__ __attribute__((aligned(16))) unsigned short lds[2][8192 + BSH];
  const int t = threadIdx.x, wave = t >> 6, lane = t & 63;
  const int m0 = blockIdx.x * 128, n0 = blockIdx.y * BN;
  const int wm = wave >> 1, wn = wave & 1;

  int srowA[4], scolA[4];
  #pragma unroll
  for (int j = 0; j < 4; ++j) {
    const int c = j * 256 + wave * 64 + lane;
    const int r = c >> 3;
    srowA[j] = r;
    scolA[j] = ((c & 7) ^ (r & 7)) << 3;
  }
  const unsigned short* aBase = A + (size_t)m0 * K;
  const unsigned short* bBase = Bt + (size_t)n0 * K;

  const int xk0 = (((lane >> 4)    ) ^ (lane & 7)) << 3;
  const int xk1 = (((lane >> 4) | 4) ^ (lane & 7)) << 3;
  const int arow = (wm * 64 + (lane & 15)) * 64;
  const int brow = (wn * (BN / 2) + (lane & 15)) * 64;

  f32x4 acc[4][NI] = {};
  const int nk = K >> 6;
  constexpr int BJ = NI;

  {
    unsigned short* l = &lds[0][0];
    #pragma unroll
    for (int j = 0; j < 4; ++j)
      gload_lds16(aBase + (size_t)srowA[j] * K + scolA[j], l + j * 2048 + wave * 512);
    #pragma unroll
    for (int j = 0; j < BJ; ++j)
      gload_lds16(bBase + (size_t)srowA[j] * K + scolA[j], l + 8192 + j * 2048 + wave * 512);
  }
  __syncthreads();

  int cur = 0;
  for (int kt = 0; kt < nk; ++kt) {
    if (kt + 1 < nk) {
      unsigned short* l = &lds[cur ^ 1][0];
      const int ko = (kt + 1) * 64;
      #pragma unroll
      for (int j = 0; j < 4; ++j)
        gload_lds16(aBase + (size_t)srowA[j] * K + ko + scolA[j], l + j * 2048 + wave * 512);
      #pragma unroll
      for (int j = 0; j < BJ; ++j)
        gload_lds16(bBase + (size_t)srowA[j] * K + ko + scolA[j], l + 8192 + j * 2048 + wave * 512);
    }
    const unsigned short* l = &lds[cur][0];
    #pragma unroll
    for (int kc = 0; kc < 2; ++kc) {
      const int xk = kc ? xk1 : xk0;
      bf16x8 a[4], b[NI];
      #pragma unroll
      for (int mi = 0; mi < 4; ++mi) a[mi] = ldb8(&l[arow + mi * 1024 + xk]);
      #pragma unroll
      for (int ni = 0; ni < NI; ++ni) b[ni] = ldb8(&l[8192 + brow + ni * 1024 + xk]);
      __builtin_amdgcn_s_setprio(1);
      #pragma unroll
      for (int mi = 0; mi < 4; ++mi)
        #pragma unroll
        for (int ni = 0; ni < NI; ++ni)
          acc[mi][ni] = mfma16(a[mi], b[ni], acc[mi][ni]);
      __builtin_amdgcn_s_setprio(0);
    }
    __syncthreads();
    cur ^= 1;
  }

  const int mrow = m0 + wm * 64 + (lane >> 4) * 4;
  const int ncol = n0 + wn * (BN / 2) + (lane & 15);
  float scl = 0.f;
  if constexpr (MODE == 2) scl = scale_p[0];
  #pragma unroll
  for (int ni = 0; ni < NI; ++ni) {
    const int n = ncol + ni * 16;
    const float bn = bias[n];
    #pragma unroll
    for (int mi = 0; mi < 4; ++mi) {
      #pragma unroll
      for (int r = 0; r < 4; ++r) {
        const size_t idx = (size_t)(mrow + mi * 16 + r) * N + n;
        float v = acc[mi][ni][r] + bn;
        if constexpr (MODE == 1) {
          v = 0.5f * v * (1.0f + erff(v * 0.70710678118f));
          outb[idx] = f2bf(v);
        } else if constexpr (MODE == 2) {
          xout[idx] = xin[idx] + scl * v;      // re-zero residual, fp32
        } else {
          outb[idx] = f2bf(v);
        }
      }
    }
  }
}

// ---------------------------------------------------------------------------
// Flash attention v8: balanced in-block KV-split + swapped QK^T/PV (O^T).
// grid = 2048 (= 32 pairs x 64 bh), block = 256 (4 waves).
// Block owns q-tile pair (qtA=p, qtB=63-p) = 17 KV-tiles total. Each q-tile
// is split across 2 waves (halves; max chain 8 tiles). Role assignment
// alternates with p&1 for per-SIMD balance. Partials (O^T,m,l) merged via
// LDS with one barrier; merge weights e=exp(m-mm) (empty half -> e=0).
// ---------------------------------------------------------------------------
__global__ __launch_bounds__(256) void attn_kernel(
    const unsigned short* __restrict__ qkv, const unsigned short* __restrict__ vT,
    unsigned short* __restrict__ vals) {
  const int bh = blockIdx.x & 63;
  const int p  = blockIdx.x >> 6;             // pair index 0..31
  const int b = bh >> 4, h = bh & 15;
  const int t = threadIdx.x, wave = t >> 6, lane = t & 63;
  const int rowLane = lane & 15, grp = lane >> 4;

  const int s01 = ((wave >> 1) ^ (p & 1)) & 1;  // which q-tile of the pair
  const int u   = wave & 1;                     // half index within q-tile
  const int qt  = s01 ? (63 - p) : p;
  const int q0  = qt * 16;
  const int nkt = (qt >> 2) + 1;                // KV64 tiles for this q-tile
  const int hlf = (nkt + 1) >> 1;
  const int kt0   = u ? hlf : 0;
  const int ktEnd = u ? nkt : hlf;

  __shared__ float Om[2][16][68];               // partner partial O^T (padded)
  __shared__ float Ml[2][16][2];                // partner (m, l)

  const unsigned short* qkvB  = qkv + (size_t)b * 1024 * 3072;
  const unsigned short* kBase = qkvB + 1024 + h * 64 + grp * 8;
  const unsigned short* vHead = vT + (size_t)bh * 64 * 1024;

  const unsigned short* qb = qkvB + (size_t)(q0 + rowLane) * 3072 + h * 64 + grp * 8;
  const bf16x8 aq0 = ldb8(qb);
  const bf16x8 aq1 = ldb8(qb + 32);

  f32x4 oaccT[4] = {};                        // O[q=q0+rowLane][d=df*16+grp*4+r]
  float mrun = -1e30f, lrun = 0.f;            // for q = q0 + rowLane

  bf16x8 k0[4], k1[4];
  if (kt0 < ktEnd) {
    #pragma unroll
    for (int nf = 0; nf < 4; ++nf) {
      const unsigned short* kb = kBase + (size_t)(kt0 * 64 + nf * 16 + rowLane) * 3072;
      k0[nf] = ldb8(kb); k1[nf] = ldb8(kb + 32);
    }
  }

  const int srcA = rowLane + ((grp & 1) << 5);  // pull lane for blocks 2g
  const int srcB = srcA + 16;                   // pull lane for blocks 2g+1
  const bool hiG = (grp >= 2);                  // selects nf register pair

  for (int kt = kt0; kt < ktEnd; ++kt) {
    const int kv0 = kt * 64;
    bf16x8 v0[4], v1[4];
    #pragma unroll
    for (int df = 0; df < 4; ++df) {
      const unsigned short* vb = vHead + (size_t)(df * 16 + rowLane) * 1024 + kv0 + grp * 8;
      v0[df] = ldb8(vb); v1[df] = ldb8(vb + 32);
    }
    // ---- S^T = (K Q^T): lane holds S[q=rowLane][kv=nf*16+grp*4+r] ----
    f32x4 sacc[4];
    #pragma unroll
    for (int nf = 0; nf < 4; ++nf) {
      f32x4 z = {0.f, 0.f, 0.f, 0.f};
      z = mfma16(k0[nf], aq0, z);
      z = mfma16(k1[nf], aq1, z);
      sacc[nf] = z;
    }
    if (kt + 1 < ktEnd) {                      // K regs dead -> prefetch next
      #pragma unroll
      for (int nf = 0; nf < 4; ++nf) {
        const unsigned short* kb = kBase + (size_t)(kv0 + 64 + nf * 16 + rowLane) * 3072;
        k0[nf] = ldb8(kb); k1[nf] = ldb8(kb + 32);
      }
    }
    float pl[4][4];
    #pragma unroll
    for (int nf = 0; nf < 4; ++nf)
      #pragma unroll
      for (int r = 0; r < 4; ++r) pl[nf][r] = sacc[nf][r] * 0.125f;
    if (kt == nkt - 1) {                       // diagonal-tile mask
      const int qg = q0 + rowLane;
      #pragma unroll
      for (int nf = 0; nf < 4; ++nf)
        #pragma unroll
        for (int r = 0; r < 4; ++r)
          if (kv0 + nf * 16 + grp * 4 + r > qg) pl[nf][r] = -1e30f;
    }
    // ---- softmax for q = rowLane (16 local + 2+2 shfl) ----
    float mloc = pl[0][0];
    #pragma unroll
    for (int nf = 0; nf < 4; ++nf)
      #pragma unroll
      for (int r = 0; r < 4; ++r) mloc = fmaxf(mloc, pl[nf][r]);
    mloc = fmaxf(mloc, __shfl_xor(mloc, 16));
    mloc = fmaxf(mloc, __shfl_xor(mloc, 32));
    const float mnew = fmaxf(mrun, mloc);
    const float facq = __expf(mrun - mnew);
    mrun = mnew;
    float sloc = 0.f;
    #pragma unroll
    for (int nf = 0; nf < 4; ++nf)
      #pragma unroll
      for (int r = 0; r < 4; ++r) {
        const float e = __expf(pl[nf][r] - mnew);
        pl[nf][r] = e;
        sloc += e;
      }
    sloc += __shfl_xor(sloc, 16);
    sloc += __shfl_xor(sloc, 32);
    lrun = lrun * facq + sloc;
    // ---- O^T rescale: per-lane, no broadcast ----
    #pragma unroll
    for (int df = 0; df < 4; ++df)
      #pragma unroll
      for (int r = 0; r < 4; ++r) oaccT[df][r] *= facq;
    // ---- P -> PV operand layout, in-register ----
    unsigned int w0[4], w1[4];
    #pragma unroll
    for (int nf = 0; nf < 4; ++nf) {
      w0[nf] = pack2bf(pl[nf][0], pl[nf][1]);
      w1[nf] = pack2bf(pl[nf][2], pl[nf][3]);
    }
    unsigned int a0, a1, a2, a3, b0, b1, b2, b3;
    {
      const int tA00 = __shfl((int)w0[0], srcA), tA01 = __shfl((int)w0[1], srcA);
      const int tA10 = __shfl((int)w1[0], srcA), tA11 = __shfl((int)w1[1], srcA);
      const int tB00 = __shfl((int)w0[0], srcB), tB01 = __shfl((int)w0[1], srcB);
      const int tB10 = __shfl((int)w1[0], srcB), tB11 = __shfl((int)w1[1], srcB);
      a0 = (unsigned)(hiG ? tA01 : tA00);
      a1 = (unsigned)(hiG ? tA11 : tA10);
      a2 = (unsigned)(hiG ? tB01 : tB00);
      a3 = (unsigned)(hiG ? tB11 : tB10);
      const int uA00 = __shfl((int)w0[2], srcA), uA01 = __shfl((int)w0[3], srcA);
      const int uA10 = __shfl((int)w1[2], srcA), uA11 = __shfl((int)w1[3], srcA);
      const int uB00 = __shfl((int)w0[2], srcB), uB01 = __shfl((int)w0[3], srcB);
      const int uB10 = __shfl((int)w1[2], srcB), uB11 = __shfl((int)w1[3], srcB);
      b0 = (unsigned)(hiG ? uA01 : uA00);
      b1 = (unsigned)(hiG ? uA11 : uA10);
      b2 = (unsigned)(hiG ? uB01 : uB00);
      b3 = (unsigned)(hiG ? uB11 : uB10);
    }
    u32x4 pa0u = {a0, a1, a2, a3};
    u32x4 pa1u = {b0, b1, b2, b3};
    const bf16x8 pa0 = __builtin_bit_cast(bf16x8, pa0u);
    const bf16x8 pa1 = __builtin_bit_cast(bf16x8, pa1u);
    // ---- O^T += V^T P^T : 8 MFMA ----
    #pragma unroll
    for (int df = 0; df < 4; ++df) {
      oaccT[df] = mfma16(v0[df], pa0, oaccT[df]);
      oaccT[df] = mfma16(v1[df], pa1, oaccT[df]);
    }
  }

  // ---- cross-wave merge: u==1 publishes, u==0 merges + writes ----
  if (u) {
    #pragma unroll
    for (int df = 0; df < 4; ++df) {
      float4 o; o.x = oaccT[df][0]; o.y = oaccT[df][1];
      o.z = oaccT[df][2]; o.w = oaccT[df][3];
      *reinterpret_cast<float4*>(&Om[s01][rowLane][df * 16 + grp * 4]) = o;
    }
    if (grp == 0) { Ml[s01][rowLane][0] = mrun; Ml[s01][rowLane][1] = lrun; }
  }
  __syncthreads();
  if (!u) {
    const float m1 = Ml[s01][rowLane][0];
    const float l1 = Ml[s01][rowLane][1];
    const float mm = fmaxf(mrun, m1);
    const float e0 = __expf(mrun - mm);
    const float e1 = __expf(m1 - mm);        // empty half: m1=-1e30 -> e1=0
    const float rl = 1.0f / (lrun * e0 + l1 * e1);
    const size_t qrow = (size_t)(b * 1024 + q0 + rowLane) * 1024 + h * 64;
    #pragma unroll
    for (int df = 0; df < 4; ++df) {
      ushort4 o;
      #pragma unroll
      for (int r = 0; r < 4; ++r) {
        const float ov = (oaccT[df][r] * e0 +
                          Om[s01][rowLane][df * 16 + grp * 4 + r] * e1) * rl;
        ((unsigned short*)&o)[r] = f2bf(ov);
      }
      *reinterpret_cast<ushort4*>(vals + qrow + df * 16 + grp * 4) = o;
    }
  }
}

// ---------------------------------------------------------------------------
extern "C" void kernel_launch(void* const* d_in, const int* in_sizes, int n_in,
                              void* d_out, int out_size, void* d_ws, size_t ws_size,
                              hipStream_t stream) {
  (void)in_sizes; (void)n_in; (void)out_size; (void)ws_size;
  const float* inputs = (const float*)d_in[0];
  const float* Wq = (const float*)d_in[1];  const float* bq = (const float*)d_in[2];
  const float* Wk = (const float*)d_in[3];  const float* bk = (const float*)d_in[4];
  const float* Wv = (const float*)d_in[5];  const float* bv = (const float*)d_in[6];
  const float* Wo = (const float*)d_in[7];  const float* bo = (const float*)d_in[8];
  const float* W1 = (const float*)d_in[9];  const float* b1 = (const float*)d_in[10];
  const float* W2 = (const float*)d_in[11]; const float* b2 = (const float*)d_in[12];
  const float* ln_g = (const float*)d_in[13];
  const float* ln_b = (const float*)d_in[14];
  const float* scale_p = (const float*)d_in[15];
  float* xbuf = (float*)d_out;               // fp32 residual stream lives here

  char* w = (char*)d_ws;
  size_t off = 0;
  auto take = [&](size_t bytes) {
    void* p = w + off;
    off = (off + bytes + 255) & ~(size_t)255;
    return p;
  };
  unsigned short* Wqkv_t = (unsigned short*)take((size_t)3072 * 1024 * 2);
  unsigned short* Wo_t   = (unsigned short*)take((size_t)1024 * 1024 * 2);
  unsigned short* W1_t   = (unsigned short*)take((size_t)4096 * 1024 * 2);
  unsigned short* W2_t   = (unsigned short*)take((size_t)1024 * 4096 * 2);
  float*          bqkv   = (float*)take(3072 * 4);
  unsigned short* rbuf   = (unsigned short*)take((size_t)4096 * 1024 * 2);
  unsigned short* qkvb   = (unsigned short*)take((size_t)4096 * 3072 * 2);
  unsigned short* vTb    = (unsigned short*)take((size_t)64 * 64 * 1024 * 2);
  unsigned short* valsb  = (unsigned short*)take((size_t)4096 * 1024 * 2);
  unsigned short* hbuf   = (unsigned short*)take((size_t)4096 * 4096 * 2);

  for (int i = 0; i < 8; ++i) {
    const float* xin = (i == 0) ? inputs : xbuf;
    // weights -> bf16, transposed [N][K]
    transpose_cvt4<<<dim3(32, 32, 4), 256, 0, stream>>>(
        Wq + (size_t)i * 1024 * 1024, Wk + (size_t)i * 1024 * 1024,
        Wv + (size_t)i * 1024 * 1024, Wo + (size_t)i * 1024 * 1024, Wqkv_t, Wo_t);
    transpose_cvt<<<dim3(32, 128), 256, 0, stream>>>(W1 + (size_t)i * 1024 * 4096, W1_t, 4096, 1024);
    transpose_cvt<<<dim3(128, 32), 256, 0, stream>>>(W2 + (size_t)i * 4096 * 1024, W2_t, 1024, 4096);
    pack_qkv_bias<<<12, 256, 0, stream>>>(bq + i * 1024, bk + i * 1024, bv + i * 1024, bqkv);
    // attention block
    ln_kernel<0><<<1024, 256, 0, stream>>>(xin, ln_g, ln_b, rbuf);
    gemm8r<3><<<192, 512, 0, stream>>>(rbuf, Wqkv_t, bqkv, qkvb, vTb, 3072, 1024);
    attn_kernel<<<2048, 256, 0, stream>>>(qkvb, vTb, valsb);
    gemm2<2, 64><<<dim3(32, 16), 256, 0, stream>>>(valsb, Wo_t, bo + i * 1024, nullptr,
                                                   xin, xbuf, scale_p, 1024, 1024);
    // FFN block
    ln_kernel<0><<<1024, 256, 0, stream>>>(xbuf, ln_g, ln_b, rbuf);
    gemm8r<1><<<256, 512, 0, stream>>>(rbuf, W1_t, b1 + i * 4096, hbuf, nullptr, 4096, 1024);
    gemm2<2, 64><<<dim3(32, 16), 256, 0, stream>>>(hbuf, W2_t, b2 + i * 1024, nullptr,
                                                   xbuf, xbuf, scale_p, 1024, 4096);
  }
  ln_kernel<1><<<1024, 256, 0, stream>>>(xbuf, ln_g, ln_b, xbuf);  // final LN, in-place
}

// Round 14
// 1846.279 us; speedup vs baseline: 1.1375x; 1.1375x over previous
//
#include <hip/hip_runtime.h>

// ---------------------------------------------------------------------------
// Transformer decoder fwd, bf16-MFMA compute, fp32 residual stream in d_out.
// L=8 B=4 S=1024 D=1024 H=16 dh=64 FC=4096. Threshold 0.1 allows bf16 GEMMs.
// QKV/W1: 256^2 ring GEMM (BK=32, 7-slot ring, counted vmcnt(4)).
// Wo/W2: proven gemm2 128x64 2-phase dbuf. LN: wave/row.
// Attn v9: 8-wave-class structure: LDS-staged K/V (gemm2-proven swizzle,
// dbuf), 32x32x16 MFMA, swapped QK^T and PV, per-lane softmax.
// ---------------------------------------------------------------------------

typedef __bf16 bf16x8 __attribute__((ext_vector_type(8)));
typedef float  f32x4  __attribute__((ext_vector_type(4)));
typedef float  f32x16 __attribute__((ext_vector_type(16)));
typedef unsigned int u32x4 __attribute__((ext_vector_type(4)));

#define DEV static __device__ __forceinline__

DEV unsigned short f2bf(float x) {
  unsigned u = __builtin_bit_cast(unsigned int, x);
  u += 0x7fffu + ((u >> 16) & 1u);          // RNE
  return (unsigned short)(u >> 16);
}

DEV unsigned int pack2bf(float lo, float hi) {
  return (unsigned int)f2bf(lo) | ((unsigned int)f2bf(hi) << 16);
}

DEV f32x4 mfma16(bf16x8 a, bf16x8 b, f32x4 c) {
  return __builtin_amdgcn_mfma_f32_16x16x32_bf16(a, b, c, 0, 0, 0);
}

DEV f32x16 mfma32(bf16x8 a, bf16x8 b, f32x16 c) {
  return __builtin_amdgcn_mfma_f32_32x32x16_bf16(a, b, c, 0, 0, 0);
}

DEV bf16x8 ldb8(const unsigned short* p) {
  return *reinterpret_cast<const bf16x8*>(p);
}

DEV void gload_lds16(const unsigned short* g, unsigned short* l) {
  __builtin_amdgcn_global_load_lds(
      (const __attribute__((address_space(1))) void*)g,
      (__attribute__((address_space(3))) void*)l, 16, 0, 0);
}

// ---------------------------------------------------------------------------
// fp32 [K][N] -> bf16 [N][K] transposed convert (32x32 LDS tile)
// ---------------------------------------------------------------------------
__global__ void transpose_cvt(const float* __restrict__ src,
                              unsigned short* __restrict__ dst,
                              int srcStride, int dstStride) {
  __shared__ float tile[32][33];
  const int t  = threadIdx.x;
  const int r  = t >> 3;
  const int c4 = (t & 7) << 2;
  const int k  = blockIdx.x * 32 + r;
  const int n0 = blockIdx.y * 32 + c4;
  const float4 v = *reinterpret_cast<const float4*>(src + (size_t)k * srcStride + n0);
  tile[r][c4] = v.x; tile[r][c4 + 1] = v.y; tile[r][c4 + 2] = v.z; tile[r][c4 + 3] = v.w;
  __syncthreads();
  const int n  = blockIdx.y * 32 + r;
  const int k0 = blockIdx.x * 32 + c4;
  ushort4 o;
  o.x = f2bf(tile[c4][r]);     o.y = f2bf(tile[c4 + 1][r]);
  o.z = f2bf(tile[c4 + 2][r]); o.w = f2bf(tile[c4 + 3][r]);
  *reinterpret_cast<ushort4*>(dst + (size_t)n * dstStride + k0) = o;
}

// 4 x (1024x1024) transposes in one dispatch (z = which matrix)
__global__ void transpose_cvt4(const float* __restrict__ Wq, const float* __restrict__ Wk,
                               const float* __restrict__ Wv, const float* __restrict__ Wo,
                               unsigned short* __restrict__ Wqkv_t,
                               unsigned short* __restrict__ Wo_t) {
  __shared__ float tile[32][33];
  const int z = blockIdx.z;
  const float* src = (z == 0) ? Wq : (z == 1) ? Wk : (z == 2) ? Wv : Wo;
  unsigned short* dst = (z == 3) ? Wo_t : (Wqkv_t + (size_t)z * 1024 * 1024);
  const int t  = threadIdx.x;
  const int r  = t >> 3;
  const int c4 = (t & 7) << 2;
  const int k  = blockIdx.x * 32 + r;
  const int n0 = blockIdx.y * 32 + c4;
  const float4 v = *reinterpret_cast<const float4*>(src + (size_t)k * 1024 + n0);
  tile[r][c4] = v.x; tile[r][c4 + 1] = v.y; tile[r][c4 + 2] = v.z; tile[r][c4 + 3] = v.w;
  __syncthreads();
  const int n  = blockIdx.y * 32 + r;
  const int k0 = blockIdx.x * 32 + c4;
  ushort4 o;
  o.x = f2bf(tile[c4][r]);     o.y = f2bf(tile[c4 + 1][r]);
  o.z = f2bf(tile[c4 + 2][r]); o.w = f2bf(tile[c4 + 3][r]);
  *reinterpret_cast<ushort4*>(dst + (size_t)n * 1024 + k0) = o;
}

__global__ void pack_qkv_bias(const float* __restrict__ bq, const float* __restrict__ bk,
                              const float* __restrict__ bv, float* __restrict__ out) {
  int i = blockIdx.x * 256 + threadIdx.x;   // 3072
  out[i] = (i < 1024) ? bq[i] : (i < 2048 ? bk[i - 1024] : bv[i - 2048]);
}

// ---------------------------------------------------------------------------
// LayerNorm v2: ONE WAVE PER ROW, 4 rows/block, grid = 1024.
// ---------------------------------------------------------------------------
template <int OUTF32>
__global__ __launch_bounds__(256) void ln_kernel(
    const float* x, const float* __restrict__ gam,
    const float* __restrict__ bet, void* out) {
  const int t = threadIdx.x, wave = t >> 6, lane = t & 63;
  const int row = blockIdx.x * 4 + wave;
  const float* xr = x + (size_t)row * 1024;
  float4 v[4];
  float s = 0.f, ss = 0.f;
  #pragma unroll
  for (int k = 0; k < 4; ++k) {
    v[k] = *reinterpret_cast<const float4*>(xr + k * 256 + lane * 4);
    s  += v[k].x + v[k].y + v[k].z + v[k].w;
    ss += v[k].x * v[k].x + v[k].y * v[k].y + v[k].z * v[k].z + v[k].w * v[k].w;
  }
  #pragma unroll
  for (int m = 1; m <= 32; m <<= 1) { s += __shfl_xor(s, m); ss += __shfl_xor(ss, m); }
  const float mean = s * (1.0f / 1024.0f);
  const float var  = ss * (1.0f / 1024.0f) - mean * mean;
  const float rstd = rsqrtf(var + 1e-5f);
  #pragma unroll
  for (int k = 0; k < 4; ++k) {
    const float4 g  = *reinterpret_cast<const float4*>(gam + k * 256 + lane * 4);
    const float4 bb = *reinterpret_cast<const float4*>(bet + k * 256 + lane * 4);
    const float y0 = (v[k].x - mean) * rstd * g.x + bb.x;
    const float y1 = (v[k].y - mean) * rstd * g.y + bb.y;
    const float y2 = (v[k].z - mean) * rstd * g.z + bb.z;
    const float y3 = (v[k].w - mean) * rstd * g.w + bb.w;
    if (OUTF32) {
      float4 o; o.x = y0; o.y = y1; o.z = y2; o.w = y3;
      *reinterpret_cast<float4*>((float*)out + (size_t)row * 1024 + k * 256 + lane * 4) = o;
    } else {
      ushort4 o; o.x = f2bf(y0); o.y = f2bf(y1); o.z = f2bf(y2); o.w = f2bf(y3);
      *reinterpret_cast<ushort4*>((unsigned short*)out + (size_t)row * 1024 + k * 256 + lane * 4) = o;
    }
  }
}

// ---------------------------------------------------------------------------
// gemm8r: 256x256 tile, BK=32, 512 thr = 8 waves. 7-slot ring; counted
// vmcnt(4); swizzle slot^=(row>>1)&3. MODE 1: bias+gelu. MODE 3: QKV split.
// ---------------------------------------------------------------------------
template <int MODE>
__global__ __launch_bounds__(512) void gemm8r(
    const unsigned short* __restrict__ A, const unsigned short* __restrict__ Bt,
    const float* __restrict__ bias, unsigned short* __restrict__ outb,
    unsigned short* __restrict__ vT, int N, int K) {
  __shared__ __attribute__((aligned(16))) unsigned short lds[7 * 8192]; // 112KB
  const int t = threadIdx.x, wave = t >> 6, lane = t & 63;
  const int wm = wave >> 2, wn = wave & 3;
  const int rl15 = lane & 15;

  const int nbn = N >> 8;
  const int qq  = gridDim.x >> 3;
  const int swz = (blockIdx.x & 7) * qq + (blockIdx.x >> 3);
  const int m0 = (swz / nbn) << 8, n0 = (swz % nbn) << 8;

  const unsigned short* aG = A  + (size_t)m0 * K;
  const unsigned short* bG = Bt + (size_t)n0 * K;

  const int srow = lane >> 2;
  const int ssl  = (((lane & 3) ^ ((srow >> 1) & 3)) << 3);   // shorts
  const int swA  = (((lane >> 4) ^ ((lane >> 1) & 3)) << 3);  // shorts

  auto stageA = [&](int slot, int kt) {
    #pragma unroll
    for (int j = 0; j < 2; ++j) {
      const int c = wave + j * 8;
      gload_lds16(aG + (size_t)(c * 16 + srow) * K + kt * 32 + ssl,
                  &lds[slot * 8192 + c * 512]);
    }
  };
  auto stageB = [&](int slot, int kt) {
    #pragma unroll
    for (int j = 0; j < 2; ++j) {
      const int c = wave + j * 8;
      gload_lds16(bG + (size_t)(c * 16 + srow) * K + kt * 32 + ssl,
                  &lds[slot * 8192 + c * 512]);
    }
  };

  const int nk = K >> 5;
  stageA(0, 0); stageB(1, 0);
  stageA(2, 1); stageB(3, 1);
  asm volatile("s_waitcnt vmcnt(4)" ::: "memory");
  asm volatile("s_barrier" ::: "memory");

  f32x4 acc[8][4] = {};
  int sA = 0, sB = 1, pA = 4, pB = 5;

  for (int kt = 0; kt < nk; ++kt) {
    const bool more = (kt + 2 < nk);
    if (more) { stageA(pA, kt + 2); stageB(pB, kt + 2); }
    const int ab = sA * 8192, bb = sB * 8192;
    bf16x8 af[8], bfr[4];
    #pragma unroll
    for (int mi = 0; mi < 8; ++mi)
      af[mi] = ldb8(&lds[ab + (wm * 128 + mi * 16 + rl15) * 32 + swA]);
    #pragma unroll
    for (int ni = 0; ni < 4; ++ni)
      bfr[ni] = ldb8(&lds[bb + (wn * 64 + ni * 16 + rl15) * 32 + swA]);
    __builtin_amdgcn_s_setprio(1);
    #pragma unroll
    for (int mi = 0; mi < 8; ++mi)
      #pragma unroll
      for (int ni = 0; ni < 4; ++ni)
        acc[mi][ni] = mfma16(af[mi], bfr[ni], acc[mi][ni]);
    __builtin_amdgcn_s_setprio(0);
    if (more) asm volatile("s_waitcnt vmcnt(4)" ::: "memory");
    else      asm volatile("s_waitcnt vmcnt(0)" ::: "memory");
    asm volatile("s_barrier" ::: "memory");
    sA += 2; if (sA >= 7) sA -= 7;
    sB += 2; if (sB >= 7) sB -= 7;
    pA += 2; if (pA >= 7) pA -= 7;
    pB += 2; if (pB >= 7) pB -= 7;
  }

  const int mrow = m0 + wm * 128 + (lane >> 4) * 4;
  const int ncol = n0 + wn * 64 + rl15;
  #pragma unroll
  for (int ni = 0; ni < 4; ++ni) {
    const int n = ncol + ni * 16;
    const float bn = bias[n];
    #pragma unroll
    for (int mi = 0; mi < 8; ++mi) {
      const int row0 = mrow + mi * 16;
      if constexpr (MODE == 3) {
        if (n >= 2048) {                               // V -> vT[b,h,d,s]
          const int h = (n - 2048) >> 6, d = (n - 2048) & 63;
          const int b = row0 >> 10, s = row0 & 1023;
          ushort4 o;
          o.x = f2bf(acc[mi][ni][0] + bn); o.y = f2bf(acc[mi][ni][1] + bn);
          o.z = f2bf(acc[mi][ni][2] + bn); o.w = f2bf(acc[mi][ni][3] + bn);
          *reinterpret_cast<ushort4*>(vT + ((size_t)(b * 16 + h) * 64 + d) * 1024 + s) = o;
          continue;
        }
      }
      #pragma unroll
      for (int r = 0; r < 4; ++r) {
        const size_t idx = (size_t)(row0 + r) * N + n;
        float v = acc[mi][ni][r] + bn;
        if constexpr (MODE == 1)
          v = 0.5f * v * (1.0f + erff(v * 0.70710678118f));  // exact GELU
        outb[idx] = f2bf(v);
      }
    }
  }
}

// ---------------------------------------------------------------------------
// GEMM v2 (proven): 128 x BN tile, BK=64, 4 waves, dbuf LDS, XOR swizzle
// chunk^=row&7. MODE 2: xout = xin + scl*(C+bias). grid (M/128, N/BN).
// ---------------------------------------------------------------------------
template <int MODE, int BN>
__global__ __launch_bounds__(256) void gemm2(
    const unsigned short* __restrict__ A, const unsigned short* __restrict__ Bt,
    const float* __restrict__ bias, unsigned short* __restrict__ outb,
    const float* xin, float* xout, const float* __restrict__ scale_p,
    int N, int K) {
  constexpr int NI = BN / 32;
  constexpr int BSH = BN * 64;
  __shared__ __attribute__((aligned(16))) unsigned short lds[2][8192 + BSH];
  const int t = threadIdx.x, wave = t >> 6, lane = t & 63;
  const int m0 = blockIdx.x * 128, n0 = blockIdx.y * BN;
  const int wm = wave >> 1, wn = wave & 1;

  int srowA[4], scolA[4];
  #pragma unroll
  for (int j = 0; j < 4; ++j) {
    const int c = j * 256 + wave * 64 + lane;
    const int r = c >> 3;
    srowA[j] = r;
    scolA[j] = ((c & 7) ^ (r & 7)) << 3;
  }
  const unsigned short* aBase = A + (size_t)m0 * K;
  const unsigned short* bBase = Bt + (size_t)n0 * K;

  const int xk0 = (((lane >> 4)    ) ^ (lane & 7)) << 3;
  const int xk1 = (((lane >> 4) | 4) ^ (lane & 7)) << 3;
  const int arow = (wm * 64 + (lane & 15)) * 64;
  const int brow = (wn * (BN / 2) + (lane & 15)) * 64;

  f32x4 acc[4][NI] = {};
  const int nk = K >> 6;
  constexpr int BJ = NI;

  {
    unsigned short* l = &lds[0][0];
    #pragma unroll
    for (int j = 0; j < 4; ++j)
      gload_lds16(aBase + (size_t)srowA[j] * K + scolA[j], l + j * 2048 + wave * 512);
    #pragma unroll
    for (int j = 0; j < BJ; ++j)
      gload_lds16(bBase + (size_t)srowA[j] * K + scolA[j], l + 8192 + j * 2048 + wave * 512);
  }
  __syncthreads();

  int cur = 0;
  for (int kt = 0; kt < nk; ++kt) {
    if (kt + 1 < nk) {
      unsigned short* l = &lds[cur ^ 1][0];
      const int ko = (kt + 1) * 64;
      #pragma unroll
      for (int j = 0; j < 4; ++j)
        gload_lds16(aBase + (size_t)srowA[j] * K + ko + scolA[j], l + j * 2048 + wave * 512);
      #pragma unroll
      for (int j = 0; j < BJ; ++j)
        gload_lds16(bBase + (size_t)srowA[j] * K + ko + scolA[j], l + 8192 + j * 2048 + wave * 512);
    }
    const unsigned short* l = &lds[cur][0];
    #pragma unroll
    for (int kc = 0; kc < 2; ++kc) {
      const int xk = kc ? xk1 : xk0;
      bf16x8 a[4], b[NI];
      #pragma unroll
      for (int mi = 0; mi < 4; ++mi) a[mi] = ldb8(&l[arow + mi * 1024 + xk]);
      #pragma unroll
      for (int ni = 0; ni < NI; ++ni) b[ni] = ldb8(&l[8192 + brow + ni * 1024 + xk]);
      __builtin_amdgcn_s_setprio(1);
      #pragma unroll
      for (int mi = 0; mi < 4; ++mi)
        #pragma unroll
        for (int ni = 0; ni < NI; ++ni)
          acc[mi][ni] = mfma16(a[mi], b[ni], acc[mi][ni]);
      __builtin_amdgcn_s_setprio(0);
    }
    __syncthreads();
    cur ^= 1;
  }

  const int mrow = m0 + wm * 64 + (lane >> 4) * 4;
  const int ncol = n0 + wn * (BN / 2) + (lane & 15);
  float scl = 0.f;
  if constexpr (MODE == 2) scl = scale_p[0];
  #pragma unroll
  for (int ni = 0; ni < NI; ++ni) {
    const int n = ncol + ni * 16;
    const float bn = bias[n];
    #pragma unroll
    for (int mi = 0; mi < 4; ++mi) {
      #pragma unroll
      for (int r = 0; r < 4; ++r) {
        const size_t idx = (size_t)(mrow + mi * 16 + r) * N + n;
        float v = acc[mi][ni][r] + bn;
        if constexpr (MODE == 1) {
          v = 0.5f * v * (1.0f + erff(v * 0.70710678118f));
          outb[idx] = f2bf(v);
        } else if constexpr (MODE == 2) {
          xout[idx] = xin[idx] + scl * v;      // re-zero residual, fp32
        } else {
          outb[idx] = f2bf(v);
        }
      }
    }
  }
}

// ---------------------------------------------------------------------------
// Flash attention v9: LDS-staged K/V + 32x32x16 MFMA, swapped QK^T and PV.
// grid = 512 (= 8 q-blocks x 64 bh, heavy first), block = 256 (4 waves).
// Block = 128 q-rows (wave w: 32 rows at qb*128+w*32); per KV64 tile the
// block cooperatively stages K[64 kv][64 dh] and V^T[64 d][64 kv] into LDS
// (gemm2-proven chunk^row&7 swizzle, dbuf, __syncthreads drains vmcnt).
// Lane q = lane&31; kv bit2 = lane>>5 (pair l<->l+32 complementary).
// Softmax per-lane: 16 local + 1 shfl_xor(32) for max and sum.
// P -> PV B-operand: 8 packs + 8 shfl_xor(32) per kv32-sub.
// ---------------------------------------------------------------------------
__global__ __launch_bounds__(256) void attn_kernel(
    const unsigned short* __restrict__ qkv, const unsigned short* __restrict__ vT,
    unsigned short* __restrict__ vals) {
  const int bh = blockIdx.x & 63;
  const int qb = 7 - (blockIdx.x >> 6);       // 7..0, heavy first
  const int b = bh >> 4, h = bh & 15;
  const int t = threadIdx.x, wave = t >> 6, lane = t & 63;
  const int l31 = lane & 31, hi = lane >> 5;
  const int q0w = qb * 128 + wave * 32;
  const int diag = q0w >> 6;                  // wave's diagonal KV64 tile
  const int nkt = qb * 2 + 2;                 // block KV64 tiles

  __shared__ __attribute__((aligned(16))) unsigned short ldsK[2][4096]; // 64x128B
  __shared__ __attribute__((aligned(16))) unsigned short ldsV[2][4096]; // 64x128B

  const unsigned short* qkvB  = qkv + (size_t)b * 1024 * 3072;
  const unsigned short* vHead = vT + (size_t)bh * 64 * 1024;

  // stage helpers: 512 chunks/tile, thread covers c = j*256 + t (j=0,1)
  const int c0row = t >> 3, c0ch = t & 7;                    // j=0 chunk
  const int c1row = (t + 256) >> 3, c1ch = t & 7;            // j=1 chunk
  const int s0col = ((c0ch ^ (c0row & 7)) << 3);             // shorts
  const int s1col = ((c1ch ^ (c1row & 7)) << 3);
  const int wbase = (t >> 6) * 512;                          // wave*64*8 shorts

  auto stageKV = [&](int buf, int kt) {
    const int kv0 = kt * 64;
    // K: rows = kv, 128B = dh*2
    gload_lds16(qkvB + (size_t)(kv0 + c0row) * 3072 + 1024 + h * 64 + s0col,
                &ldsK[buf][wbase]);
    gload_lds16(qkvB + (size_t)(kv0 + c1row) * 3072 + 1024 + h * 64 + s1col,
                &ldsK[buf][2048 + wbase]);
    // V: rows = d, 128B = 64 kv * 2
    gload_lds16(vHead + (size_t)c0row * 1024 + kv0 + s0col, &ldsV[buf][wbase]);
    gload_lds16(vHead + (size_t)c1row * 1024 + kv0 + s1col, &ldsV[buf][2048 + wbase]);
  };

  // Q fragments (B-operand): col q = q0w + l31, k = hi*8 + j + 16s
  const unsigned short* qrow = qkvB + (size_t)(q0w + l31) * 3072 + h * 64 + hi * 8;
  bf16x8 qf[4];
  #pragma unroll
  for (int s = 0; s < 4; ++s) qf[s] = ldb8(qrow + 16 * s);

  f32x16 oacc[2] = {};                        // O^T[d=db*32+rowmap][q=q0w+l31]
  float mrun = -1e30f, lrun = 0.f;

  stageKV(0, 0);
  __syncthreads();

  for (int kt = 0; kt < nkt; ++kt) {
    const int cur = kt & 1;
    if (kt + 1 < nkt) stageKV(cur ^ 1, kt + 1);
    if (kt <= diag) {
      const unsigned short* K = ldsK[cur];
      const unsigned short* V = ldsV[cur];
      #pragma unroll
      for (int sub = 0; sub < 2; ++sub) {
        const int krow = sub * 32 + l31;
        // ---- S^T = K Q^T : 4 MFMA over dh ----
        f32x16 sacc = {};
        #pragma unroll
        for (int s = 0; s < 4; ++s) {
          const bf16x8 kf = ldb8(&K[krow * 64 + (((2 * s + hi) ^ (krow & 7)) << 3)]);
          sacc = mfma32(kf, qf[s], sacc);
        }
        float p[16];
        #pragma unroll
        for (int r = 0; r < 16; ++r) p[r] = sacc[r] * 0.125f;
        if (kt == diag) {                     // causal mask (diagonal tile)
          const int qg = q0w + l31;
          #pragma unroll
          for (int r = 0; r < 16; ++r) {
            const int kv = kt * 64 + sub * 32 + (r & 3) + 8 * (r >> 2) + 4 * hi;
            if (kv > qg) p[r] = -1e30f;
          }
        }
        // ---- per-lane softmax (q = l31; pair l^32 has other kv half) ----
        float mloc = p[0];
        #pragma unroll
        for (int r = 1; r < 16; ++r) mloc = fmaxf(mloc, p[r]);
        mloc = fmaxf(mloc, __shfl_xor(mloc, 32));
        const float mnew = fmaxf(mrun, mloc);
        const float facq = __expf(mrun - mnew);
        mrun = mnew;
        float sloc = 0.f;
        #pragma unroll
        for (int r = 0; r < 16; ++r) {
          const float e = __expf(p[r] - mnew);
          p[r] = e;
          sloc += e;
        }
        sloc += __shfl_xor(sloc, 32);
        lrun = lrun * facq + sloc;
        #pragma unroll
        for (int db = 0; db < 2; ++db)
          #pragma unroll
          for (int r = 0; r < 16; ++r) oacc[db][r] *= facq;
        // ---- P -> B-operand: pack pairs, swap halves ----
        unsigned int w[8], x[8];
        #pragma unroll
        for (int i = 0; i < 8; ++i) w[i] = pack2bf(p[2 * i], p[2 * i + 1]);
        #pragma unroll
        for (int i = 0; i < 8; ++i) x[i] = (unsigned)__shfl_xor((int)w[i], 32);
        #pragma unroll
        for (int ks = 0; ks < 2; ++ks) {
          // span base = ks*16 + hi*8; q-index = base>>3 = 2ks+hi
          const int qi = 2 * ks + hi;
          u32x4 fu;
          if (hi) { fu = u32x4{x[2 * qi], x[2 * qi + 1], w[2 * qi], w[2 * qi + 1]}; }
          else    { fu = u32x4{w[2 * qi], w[2 * qi + 1], x[2 * qi], x[2 * qi + 1]}; }
          const bf16x8 pf = __builtin_bit_cast(bf16x8, fu);
          #pragma unroll
          for (int db = 0; db < 2; ++db) {
            const int vrow = db * 32 + l31;
            const int vch  = sub * 4 + ks * 2 + hi;
            const bf16x8 vf = ldb8(&V[vrow * 64 + ((vch ^ (vrow & 7)) << 3)]);
            oacc[db] = mfma32(vf, pf, oacc[db]);
          }
        }
      }
    }
    __syncthreads();                          // drains stage vmcnt + LDS reuse
  }

  // ---- epilogue: O/l, per-lane; d = db*32 + (r&3) + 8*(r>>2) + 4*hi ----
  const float rl = 1.0f / lrun;
  const size_t qrowOut = (size_t)(b * 1024 + q0w + l31) * 1024 + h * 64;
  #pragma unroll
  for (int db = 0; db < 2; ++db)
    #pragma unroll
    for (int rq = 0; rq < 4; ++rq) {
      const int d0 = db * 32 + 8 * rq + 4 * hi;
      ushort4 o;
      o.x = f2bf(oacc[db][rq * 4 + 0] * rl);
      o.y = f2bf(oacc[db][rq * 4 + 1] * rl);
      o.z = f2bf(oacc[db][rq * 4 + 2] * rl);
      o.w = f2bf(oacc[db][rq * 4 + 3] * rl);
      *reinterpret_cast<ushort4*>(vals + qrowOut + d0) = o;
    }
}

// ---------------------------------------------------------------------------
extern "C" void kernel_launch(void* const* d_in, const int* in_sizes, int n_in,
                              void* d_out, int out_size, void* d_ws, size_t ws_size,
                              hipStream_t stream) {
  (void)in_sizes; (void)n_in; (void)out_size; (void)ws_size;
  const float* inputs = (const float*)d_in[0];
  const float* Wq = (const float*)d_in[1];  const float* bq = (const float*)d_in[2];
  const float* Wk = (const float*)d_in[3];  const float* bk = (const float*)d_in[4];
  const float* Wv = (const float*)d_in[5];  const float* bv = (const float*)d_in[6];
  const float* Wo = (const float*)d_in[7];  const float* bo = (const float*)d_in[8];
  const float* W1 = (const float*)d_in[9];  const float* b1 = (const float*)d_in[10];
  const float* W2 = (const float*)d_in[11]; const float* b2 = (const float*)d_in[12];
  const float* ln_g = (const float*)d_in[13];
  const float* ln_b = (const float*)d_in[14];
  const float* scale_p = (const float*)d_in[15];
  float* xbuf = (float*)d_out;               // fp32 residual stream lives here

  char* w = (char*)d_ws;
  size_t off = 0;
  auto take = [&](size_t bytes) {
    void* p = w + off;
    off = (off + bytes + 255) & ~(size_t)255;
    return p;
  };
  unsigned short* Wqkv_t = (unsigned short*)take((size_t)3072 * 1024 * 2);
  unsigned short* Wo_t   = (unsigned short*)take((size_t)1024 * 1024 * 2);
  unsigned short* W1_t   = (unsigned short*)take((size_t)4096 * 1024 * 2);
  unsigned short* W2_t   = (unsigned short*)take((size_t)1024 * 4096 * 2);
  float*          bqkv   = (float*)take(3072 * 4);
  unsigned short* rbuf   = (unsigned short*)take((size_t)4096 * 1024 * 2);
  unsigned short* qkvb   = (unsigned short*)take((size_t)4096 * 3072 * 2);
  unsigned short* vTb    = (unsigned short*)take((size_t)64 * 64 * 1024 * 2);
  unsigned short* valsb  = (unsigned short*)take((size_t)4096 * 1024 * 2);
  unsigned short* hbuf   = (unsigned short*)take((size_t)4096 * 4096 * 2);

  for (int i = 0; i < 8; ++i) {
    const float* xin = (i == 0) ? inputs : xbuf;
    // weights -> bf16, transposed [N][K]
    transpose_cvt4<<<dim3(32, 32, 4), 256, 0, stream>>>(
        Wq + (size_t)i * 1024 * 1024, Wk + (size_t)i * 1024 * 1024,
        Wv + (size_t)i * 1024 * 1024, Wo + (size_t)i * 1024 * 1024, Wqkv_t, Wo_t);
    transpose_cvt<<<dim3(32, 128), 256, 0, stream>>>(W1 + (size_t)i * 1024 * 4096, W1_t, 4096, 1024);
    transpose_cvt<<<dim3(128, 32), 256, 0, stream>>>(W2 + (size_t)i * 4096 * 1024, W2_t, 1024, 4096);
    pack_qkv_bias<<<12, 256, 0, stream>>>(bq + i * 1024, bk + i * 1024, bv + i * 1024, bqkv);
    // attention block
    ln_kernel<0><<<1024, 256, 0, stream>>>(xin, ln_g, ln_b, rbuf);
    gemm8r<3><<<192, 512, 0, stream>>>(rbuf, Wqkv_t, bqkv, qkvb, vTb, 3072, 1024);
    attn_kernel<<<512, 256, 0, stream>>>(qkvb, vTb, valsb);
    gemm2<2, 64><<<dim3(32, 16), 256, 0, stream>>>(valsb, Wo_t, bo + i * 1024, nullptr,
                                                   xin, xbuf, scale_p, 1024, 1024);
    // FFN block
    ln_kernel<0><<<1024, 256, 0, stream>>>(xbuf, ln_g, ln_b, rbuf);
    gemm8r<1><<<256, 512, 0, stream>>>(rbuf, W1_t, b1 + i * 4096, hbuf, nullptr, 4096, 1024);
    gemm2<2, 64><<<dim3(32, 16), 256, 0, stream>>>(hbuf, W2_t, b2 + i * 1024, nullptr,
                                                   xbuf, xbuf, scale_p, 1024, 4096);
  }
  ln_kernel<1><<<1024, 256, 0, stream>>>(xbuf, ln_g, ln_b, xbuf);  // final LN, in-place
}

// Round 15
// 1808.342 us; speedup vs baseline: 1.1614x; 1.0210x over previous
//
#include <hip/hip_runtime.h>

// ---------------------------------------------------------------------------
// Transformer decoder fwd, bf16-MFMA compute, fp32 residual stream in d_out.
// L=8 B=4 S=1024 D=1024 H=16 dh=64 FC=4096. Threshold 0.1 allows bf16 GEMMs.
// QKV/W1: 256^2 ring GEMM (BK=32, 7-slot ring, counted vmcnt(4)).
// Wo/W2: gemm4k = gemm2 (128x64, BK=64, proven swizzle) + 3+3-slot LDS ring,
// stage t+2, counted vmcnt(6) (T4). LN: wave/row.
// Attn: v9 (LDS-staged K/V, 32x32 MFMA, swapped QK^T/PV, per-lane softmax).
// ---------------------------------------------------------------------------

typedef __bf16 bf16x8 __attribute__((ext_vector_type(8)));
typedef float  f32x4  __attribute__((ext_vector_type(4)));
typedef float  f32x16 __attribute__((ext_vector_type(16)));
typedef unsigned int u32x4 __attribute__((ext_vector_type(4)));

#define DEV static __device__ __forceinline__

DEV unsigned short f2bf(float x) {
  unsigned u = __builtin_bit_cast(unsigned int, x);
  u += 0x7fffu + ((u >> 16) & 1u);          // RNE
  return (unsigned short)(u >> 16);
}

DEV unsigned int pack2bf(float lo, float hi) {
  return (unsigned int)f2bf(lo) | ((unsigned int)f2bf(hi) << 16);
}

DEV f32x4 mfma16(bf16x8 a, bf16x8 b, f32x4 c) {
  return __builtin_amdgcn_mfma_f32_16x16x32_bf16(a, b, c, 0, 0, 0);
}

DEV f32x16 mfma32(bf16x8 a, bf16x8 b, f32x16 c) {
  return __builtin_amdgcn_mfma_f32_32x32x16_bf16(a, b, c, 0, 0, 0);
}

DEV bf16x8 ldb8(const unsigned short* p) {
  return *reinterpret_cast<const bf16x8*>(p);
}

DEV void gload_lds16(const unsigned short* g, unsigned short* l) {
  __builtin_amdgcn_global_load_lds(
      (const __attribute__((address_space(1))) void*)g,
      (__attribute__((address_space(3))) void*)l, 16, 0, 0);
}

// ---------------------------------------------------------------------------
// fp32 [K][N] -> bf16 [N][K] transposed convert (32x32 LDS tile)
// ---------------------------------------------------------------------------
__global__ void transpose_cvt(const float* __restrict__ src,
                              unsigned short* __restrict__ dst,
                              int srcStride, int dstStride) {
  __shared__ float tile[32][33];
  const int t  = threadIdx.x;
  const int r  = t >> 3;
  const int c4 = (t & 7) << 2;
  const int k  = blockIdx.x * 32 + r;
  const int n0 = blockIdx.y * 32 + c4;
  const float4 v = *reinterpret_cast<const float4*>(src + (size_t)k * srcStride + n0);
  tile[r][c4] = v.x; tile[r][c4 + 1] = v.y; tile[r][c4 + 2] = v.z; tile[r][c4 + 3] = v.w;
  __syncthreads();
  const int n  = blockIdx.y * 32 + r;
  const int k0 = blockIdx.x * 32 + c4;
  ushort4 o;
  o.x = f2bf(tile[c4][r]);     o.y = f2bf(tile[c4 + 1][r]);
  o.z = f2bf(tile[c4 + 2][r]); o.w = f2bf(tile[c4 + 3][r]);
  *reinterpret_cast<ushort4*>(dst + (size_t)n * dstStride + k0) = o;
}

// 4 x (1024x1024) transposes in one dispatch (z = which matrix)
__global__ void transpose_cvt4(const float* __restrict__ Wq, const float* __restrict__ Wk,
                               const float* __restrict__ Wv, const float* __restrict__ Wo,
                               unsigned short* __restrict__ Wqkv_t,
                               unsigned short* __restrict__ Wo_t) {
  __shared__ float tile[32][33];
  const int z = blockIdx.z;
  const float* src = (z == 0) ? Wq : (z == 1) ? Wk : (z == 2) ? Wv : Wo;
  unsigned short* dst = (z == 3) ? Wo_t : (Wqkv_t + (size_t)z * 1024 * 1024);
  const int t  = threadIdx.x;
  const int r  = t >> 3;
  const int c4 = (t & 7) << 2;
  const int k  = blockIdx.x * 32 + r;
  const int n0 = blockIdx.y * 32 + c4;
  const float4 v = *reinterpret_cast<const float4*>(src + (size_t)k * 1024 + n0);
  tile[r][c4] = v.x; tile[r][c4 + 1] = v.y; tile[r][c4 + 2] = v.z; tile[r][c4 + 3] = v.w;
  __syncthreads();
  const int n  = blockIdx.y * 32 + r;
  const int k0 = blockIdx.x * 32 + c4;
  ushort4 o;
  o.x = f2bf(tile[c4][r]);     o.y = f2bf(tile[c4 + 1][r]);
  o.z = f2bf(tile[c4 + 2][r]); o.w = f2bf(tile[c4 + 3][r]);
  *reinterpret_cast<ushort4*>(dst + (size_t)n * 1024 + k0) = o;
}

__global__ void pack_qkv_bias(const float* __restrict__ bq, const float* __restrict__ bk,
                              const float* __restrict__ bv, float* __restrict__ out) {
  int i = blockIdx.x * 256 + threadIdx.x;   // 3072
  out[i] = (i < 1024) ? bq[i] : (i < 2048 ? bk[i - 1024] : bv[i - 2048]);
}

// ---------------------------------------------------------------------------
// LayerNorm v2: ONE WAVE PER ROW, 4 rows/block, grid = 1024.
// ---------------------------------------------------------------------------
template <int OUTF32>
__global__ __launch_bounds__(256) void ln_kernel(
    const float* x, const float* __restrict__ gam,
    const float* __restrict__ bet, void* out) {
  const int t = threadIdx.x, wave = t >> 6, lane = t & 63;
  const int row = blockIdx.x * 4 + wave;
  const float* xr = x + (size_t)row * 1024;
  float4 v[4];
  float s = 0.f, ss = 0.f;
  #pragma unroll
  for (int k = 0; k < 4; ++k) {
    v[k] = *reinterpret_cast<const float4*>(xr + k * 256 + lane * 4);
    s  += v[k].x + v[k].y + v[k].z + v[k].w;
    ss += v[k].x * v[k].x + v[k].y * v[k].y + v[k].z * v[k].z + v[k].w * v[k].w;
  }
  #pragma unroll
  for (int m = 1; m <= 32; m <<= 1) { s += __shfl_xor(s, m); ss += __shfl_xor(ss, m); }
  const float mean = s * (1.0f / 1024.0f);
  const float var  = ss * (1.0f / 1024.0f) - mean * mean;
  const float rstd = rsqrtf(var + 1e-5f);
  #pragma unroll
  for (int k = 0; k < 4; ++k) {
    const float4 g  = *reinterpret_cast<const float4*>(gam + k * 256 + lane * 4);
    const float4 bb = *reinterpret_cast<const float4*>(bet + k * 256 + lane * 4);
    const float y0 = (v[k].x - mean) * rstd * g.x + bb.x;
    const float y1 = (v[k].y - mean) * rstd * g.y + bb.y;
    const float y2 = (v[k].z - mean) * rstd * g.z + bb.z;
    const float y3 = (v[k].w - mean) * rstd * g.w + bb.w;
    if (OUTF32) {
      float4 o; o.x = y0; o.y = y1; o.z = y2; o.w = y3;
      *reinterpret_cast<float4*>((float*)out + (size_t)row * 1024 + k * 256 + lane * 4) = o;
    } else {
      ushort4 o; o.x = f2bf(y0); o.y = f2bf(y1); o.z = f2bf(y2); o.w = f2bf(y3);
      *reinterpret_cast<ushort4*>((unsigned short*)out + (size_t)row * 1024 + k * 256 + lane * 4) = o;
    }
  }
}

// ---------------------------------------------------------------------------
// gemm8r: 256x256 tile, BK=32, 512 thr = 8 waves. 7-slot ring; counted
// vmcnt(4); swizzle slot^=(row>>1)&3. MODE 1: bias+gelu. MODE 3: QKV split.
// ---------------------------------------------------------------------------
template <int MODE>
__global__ __launch_bounds__(512) void gemm8r(
    const unsigned short* __restrict__ A, const unsigned short* __restrict__ Bt,
    const float* __restrict__ bias, unsigned short* __restrict__ outb,
    unsigned short* __restrict__ vT, int N, int K) {
  __shared__ __attribute__((aligned(16))) unsigned short lds[7 * 8192]; // 112KB
  const int t = threadIdx.x, wave = t >> 6, lane = t & 63;
  const int wm = wave >> 2, wn = wave & 3;
  const int rl15 = lane & 15;

  const int nbn = N >> 8;
  const int qq  = gridDim.x >> 3;
  const int swz = (blockIdx.x & 7) * qq + (blockIdx.x >> 3);
  const int m0 = (swz / nbn) << 8, n0 = (swz % nbn) << 8;

  const unsigned short* aG = A  + (size_t)m0 * K;
  const unsigned short* bG = Bt + (size_t)n0 * K;

  const int srow = lane >> 2;
  const int ssl  = (((lane & 3) ^ ((srow >> 1) & 3)) << 3);   // shorts
  const int swA  = (((lane >> 4) ^ ((lane >> 1) & 3)) << 3);  // shorts

  auto stageA = [&](int slot, int kt) {
    #pragma unroll
    for (int j = 0; j < 2; ++j) {
      const int c = wave + j * 8;
      gload_lds16(aG + (size_t)(c * 16 + srow) * K + kt * 32 + ssl,
                  &lds[slot * 8192 + c * 512]);
    }
  };
  auto stageB = [&](int slot, int kt) {
    #pragma unroll
    for (int j = 0; j < 2; ++j) {
      const int c = wave + j * 8;
      gload_lds16(bG + (size_t)(c * 16 + srow) * K + kt * 32 + ssl,
                  &lds[slot * 8192 + c * 512]);
    }
  };

  const int nk = K >> 5;
  stageA(0, 0); stageB(1, 0);
  stageA(2, 1); stageB(3, 1);
  asm volatile("s_waitcnt vmcnt(4)" ::: "memory");
  asm volatile("s_barrier" ::: "memory");

  f32x4 acc[8][4] = {};
  int sA = 0, sB = 1, pA = 4, pB = 5;

  for (int kt = 0; kt < nk; ++kt) {
    const bool more = (kt + 2 < nk);
    if (more) { stageA(pA, kt + 2); stageB(pB, kt + 2); }
    const int ab = sA * 8192, bb = sB * 8192;
    bf16x8 af[8], bfr[4];
    #pragma unroll
    for (int mi = 0; mi < 8; ++mi)
      af[mi] = ldb8(&lds[ab + (wm * 128 + mi * 16 + rl15) * 32 + swA]);
    #pragma unroll
    for (int ni = 0; ni < 4; ++ni)
      bfr[ni] = ldb8(&lds[bb + (wn * 64 + ni * 16 + rl15) * 32 + swA]);
    __builtin_amdgcn_s_setprio(1);
    #pragma unroll
    for (int mi = 0; mi < 8; ++mi)
      #pragma unroll
      for (int ni = 0; ni < 4; ++ni)
        acc[mi][ni] = mfma16(af[mi], bfr[ni], acc[mi][ni]);
    __builtin_amdgcn_s_setprio(0);
    if (more) asm volatile("s_waitcnt vmcnt(4)" ::: "memory");
    else      asm volatile("s_waitcnt vmcnt(0)" ::: "memory");
    asm volatile("s_barrier" ::: "memory");
    sA += 2; if (sA >= 7) sA -= 7;
    sB += 2; if (sB >= 7) sB -= 7;
    pA += 2; if (pA >= 7) pA -= 7;
    pB += 2; if (pB >= 7) pB -= 7;
  }

  const int mrow = m0 + wm * 128 + (lane >> 4) * 4;
  const int ncol = n0 + wn * 64 + rl15;
  #pragma unroll
  for (int ni = 0; ni < 4; ++ni) {
    const int n = ncol + ni * 16;
    const float bn = bias[n];
    #pragma unroll
    for (int mi = 0; mi < 8; ++mi) {
      const int row0 = mrow + mi * 16;
      if constexpr (MODE == 3) {
        if (n >= 2048) {                               // V -> vT[b,h,d,s]
          const int h = (n - 2048) >> 6, d = (n - 2048) & 63;
          const int b = row0 >> 10, s = row0 & 1023;
          ushort4 o;
          o.x = f2bf(acc[mi][ni][0] + bn); o.y = f2bf(acc[mi][ni][1] + bn);
          o.z = f2bf(acc[mi][ni][2] + bn); o.w = f2bf(acc[mi][ni][3] + bn);
          *reinterpret_cast<ushort4*>(vT + ((size_t)(b * 16 + h) * 64 + d) * 1024 + s) = o;
          continue;
        }
      }
      #pragma unroll
      for (int r = 0; r < 4; ++r) {
        const size_t idx = (size_t)(row0 + r) * N + n;
        float v = acc[mi][ni][r] + bn;
        if constexpr (MODE == 1)
          v = 0.5f * v * (1.0f + erff(v * 0.70710678118f));  // exact GELU
        outb[idx] = f2bf(v);
      }
    }
  }
}

// ---------------------------------------------------------------------------
// gemm4k: 128x64 tile, BK=64, 4 waves (2x2, per-wave 64x32). LDS ring:
// 3 A-slots (16KB) + 3 B-slots (8KB) = 72KB -> 2 blocks/CU at grid 512.
// Stage t+2 at loop top; boundary = counted vmcnt(6) + raw s_barrier
// (T4: loads get ~2 tile-times to land; never drain-0 mid-loop).
// Swizzle + fragment addressing identical to proven gemm2.
// MODE 2: xout = xin + scl*(C+bias) (f32 residual). grid (M/128, N/64).
// ---------------------------------------------------------------------------
template <int MODE>
__global__ __launch_bounds__(256) void gemm4k(
    const unsigned short* __restrict__ A, const unsigned short* __restrict__ Bt,
    const float* __restrict__ bias, unsigned short* __restrict__ outb,
    const float* xin, float* xout, const float* __restrict__ scale_p,
    int N, int K) {
  __shared__ __attribute__((aligned(16))) unsigned short lds[36864]; // 72KB
  const int t = threadIdx.x, wave = t >> 6, lane = t & 63;
  const int m0 = blockIdx.x * 128, n0 = blockIdx.y * 64;
  const int wm = wave >> 1, wn = wave & 1;

  // staging map (gemm2-proven): chunk c -> row c>>3, 16B slot (c&7)^(row&7)
  int srowA[4], scolA[4];
  #pragma unroll
  for (int j = 0; j < 4; ++j) {
    const int c = j * 256 + wave * 64 + lane;
    const int r = c >> 3;
    srowA[j] = r;
    scolA[j] = ((c & 7) ^ (r & 7)) << 3;
  }
  const unsigned short* aBase = A + (size_t)m0 * K;
  const unsigned short* bBase = Bt + (size_t)n0 * K;

  const int xk0 = (((lane >> 4)    ) ^ (lane & 7)) << 3;
  const int xk1 = (((lane >> 4) | 4) ^ (lane & 7)) << 3;
  const int arow = (wm * 64 + (lane & 15)) * 64;
  const int brow = (wn * 32 + (lane & 15)) * 64;

  auto stage = [&](int slot, int kt) {              // 6 gloads/thread-inst
    unsigned short* lA = &lds[slot * 8192];
    unsigned short* lB = &lds[24576 + slot * 4096];
    const int ko = kt * 64;
    #pragma unroll
    for (int j = 0; j < 4; ++j)
      gload_lds16(aBase + (size_t)srowA[j] * K + ko + scolA[j],
                  lA + j * 2048 + wave * 512);
    #pragma unroll
    for (int j = 0; j < 2; ++j)
      gload_lds16(bBase + (size_t)srowA[j] * K + ko + scolA[j],
                  lB + j * 2048 + wave * 512);
  };

  f32x4 acc[4][2] = {};
  const int nk = K >> 6;

  stage(0, 0); stage(1, 1);
  asm volatile("s_waitcnt vmcnt(6)" ::: "memory");  // tile 0 landed
  asm volatile("s_barrier" ::: "memory");

  int cs = 0;
  for (int kt = 0; kt < nk; ++kt) {
    const bool more = (kt + 2 < nk);
    if (more) { int ps = cs + 2; if (ps >= 3) ps -= 3; stage(ps, kt + 2); }
    const unsigned short* lA = &lds[cs * 8192];
    const unsigned short* lB = &lds[24576 + cs * 4096];
    #pragma unroll
    for (int kc = 0; kc < 2; ++kc) {
      const int xk = kc ? xk1 : xk0;
      bf16x8 a[4], b[2];
      #pragma unroll
      for (int mi = 0; mi < 4; ++mi) a[mi] = ldb8(&lA[arow + mi * 1024 + xk]);
      #pragma unroll
      for (int ni = 0; ni < 2; ++ni) b[ni] = ldb8(&lB[brow + ni * 1024 + xk]);
      __builtin_amdgcn_s_setprio(1);
      #pragma unroll
      for (int mi = 0; mi < 4; ++mi)
        #pragma unroll
        for (int ni = 0; ni < 2; ++ni)
          acc[mi][ni] = mfma16(a[mi], b[ni], acc[mi][ni]);
      __builtin_amdgcn_s_setprio(0);
    }
    if (more) asm volatile("s_waitcnt vmcnt(6)" ::: "memory"); // t+1 landed
    else      asm volatile("s_waitcnt vmcnt(0)" ::: "memory");
    asm volatile("s_barrier" ::: "memory");
    ++cs; if (cs == 3) cs = 0;
  }

  const int mrow = m0 + wm * 64 + (lane >> 4) * 4;
  const int ncol = n0 + wn * 32 + (lane & 15);
  float scl = 0.f;
  if constexpr (MODE == 2) scl = scale_p[0];
  #pragma unroll
  for (int ni = 0; ni < 2; ++ni) {
    const int n = ncol + ni * 16;
    const float bn = bias[n];
    #pragma unroll
    for (int mi = 0; mi < 4; ++mi) {
      #pragma unroll
      for (int r = 0; r < 4; ++r) {
        const size_t idx = (size_t)(mrow + mi * 16 + r) * N + n;
        float v = acc[mi][ni][r] + bn;
        if constexpr (MODE == 2) {
          xout[idx] = xin[idx] + scl * v;      // re-zero residual, fp32
        } else {
          outb[idx] = f2bf(v);
        }
      }
    }
  }
}

// ---------------------------------------------------------------------------
// Flash attention v9: LDS-staged K/V + 32x32x16 MFMA, swapped QK^T and PV.
// grid = 512 (= 8 q-blocks x 64 bh, heavy first), block = 256 (4 waves).
// ---------------------------------------------------------------------------
__global__ __launch_bounds__(256) void attn_kernel(
    const unsigned short* __restrict__ qkv, const unsigned short* __restrict__ vT,
    unsigned short* __restrict__ vals) {
  const int bh = blockIdx.x & 63;
  const int qb = 7 - (blockIdx.x >> 6);       // 7..0, heavy first
  const int b = bh >> 4, h = bh & 15;
  const int t = threadIdx.x, wave = t >> 6, lane = t & 63;
  const int l31 = lane & 31, hi = lane >> 5;
  const int q0w = qb * 128 + wave * 32;
  const int diag = q0w >> 6;                  // wave's diagonal KV64 tile
  const int nkt = qb * 2 + 2;                 // block KV64 tiles

  __shared__ __attribute__((aligned(16))) unsigned short ldsK[2][4096]; // 64x128B
  __shared__ __attribute__((aligned(16))) unsigned short ldsV[2][4096]; // 64x128B

  const unsigned short* qkvB  = qkv + (size_t)b * 1024 * 3072;
  const unsigned short* vHead = vT + (size_t)bh * 64 * 1024;

  const int c0row = t >> 3, c0ch = t & 7;
  const int c1row = (t + 256) >> 3, c1ch = t & 7;
  const int s0col = ((c0ch ^ (c0row & 7)) << 3);
  const int s1col = ((c1ch ^ (c1row & 7)) << 3);
  const int wbase = (t >> 6) * 512;

  auto stageKV = [&](int buf, int kt) {
    const int kv0 = kt * 64;
    gload_lds16(qkvB + (size_t)(kv0 + c0row) * 3072 + 1024 + h * 64 + s0col,
                &ldsK[buf][wbase]);
    gload_lds16(qkvB + (size_t)(kv0 + c1row) * 3072 + 1024 + h * 64 + s1col,
                &ldsK[buf][2048 + wbase]);
    gload_lds16(vHead + (size_t)c0row * 1024 + kv0 + s0col, &ldsV[buf][wbase]);
    gload_lds16(vHead + (size_t)c1row * 1024 + kv0 + s1col, &ldsV[buf][2048 + wbase]);
  };

  const unsigned short* qrow = qkvB + (size_t)(q0w + l31) * 3072 + h * 64 + hi * 8;
  bf16x8 qf[4];
  #pragma unroll
  for (int s = 0; s < 4; ++s) qf[s] = ldb8(qrow + 16 * s);

  f32x16 oacc[2] = {};
  float mrun = -1e30f, lrun = 0.f;

  stageKV(0, 0);
  __syncthreads();

  for (int kt = 0; kt < nkt; ++kt) {
    const int cur = kt & 1;
    if (kt + 1 < nkt) stageKV(cur ^ 1, kt + 1);
    if (kt <= diag) {
      const unsigned short* K = ldsK[cur];
      const unsigned short* V = ldsV[cur];
      #pragma unroll
      for (int sub = 0; sub < 2; ++sub) {
        const int krow = sub * 32 + l31;
        f32x16 sacc = {};
        #pragma unroll
        for (int s = 0; s < 4; ++s) {
          const bf16x8 kf = ldb8(&K[krow * 64 + (((2 * s + hi) ^ (krow & 7)) << 3)]);
          sacc = mfma32(kf, qf[s], sacc);
        }
        float p[16];
        #pragma unroll
        for (int r = 0; r < 16; ++r) p[r] = sacc[r] * 0.125f;
        if (kt == diag) {
          const int qg = q0w + l31;
          #pragma unroll
          for (int r = 0; r < 16; ++r) {
            const int kv = kt * 64 + sub * 32 + (r & 3) + 8 * (r >> 2) + 4 * hi;
            if (kv > qg) p[r] = -1e30f;
          }
        }
        float mloc = p[0];
        #pragma unroll
        for (int r = 1; r < 16; ++r) mloc = fmaxf(mloc, p[r]);
        mloc = fmaxf(mloc, __shfl_xor(mloc, 32));
        const float mnew = fmaxf(mrun, mloc);
        const float facq = __expf(mrun - mnew);
        mrun = mnew;
        float sloc = 0.f;
        #pragma unroll
        for (int r = 0; r < 16; ++r) {
          const float e = __expf(p[r] - mnew);
          p[r] = e;
          sloc += e;
        }
        sloc += __shfl_xor(sloc, 32);
        lrun = lrun * facq + sloc;
        #pragma unroll
        for (int db = 0; db < 2; ++db)
          #pragma unroll
          for (int r = 0; r < 16; ++r) oacc[db][r] *= facq;
        unsigned int w[8], x[8];
        #pragma unroll
        for (int i = 0; i < 8; ++i) w[i] = pack2bf(p[2 * i], p[2 * i + 1]);
        #pragma unroll
        for (int i = 0; i < 8; ++i) x[i] = (unsigned)__shfl_xor((int)w[i], 32);
        #pragma unroll
        for (int ks = 0; ks < 2; ++ks) {
          const int qi = 2 * ks + hi;
          u32x4 fu;
          if (hi) { fu = u32x4{x[2 * qi], x[2 * qi + 1], w[2 * qi], w[2 * qi + 1]}; }
          else    { fu = u32x4{w[2 * qi], w[2 * qi + 1], x[2 * qi], x[2 * qi + 1]}; }
          const bf16x8 pf = __builtin_bit_cast(bf16x8, fu);
          #pragma unroll
          for (int db = 0; db < 2; ++db) {
            const int vrow = db * 32 + l31;
            const int vch  = sub * 4 + ks * 2 + hi;
            const bf16x8 vf = ldb8(&V[vrow * 64 + ((vch ^ (vrow & 7)) << 3)]);
            oacc[db] = mfma32(vf, pf, oacc[db]);
          }
        }
      }
    }
    __syncthreads();
  }

  const float rl = 1.0f / lrun;
  const size_t qrowOut = (size_t)(b * 1024 + q0w + l31) * 1024 + h * 64;
  #pragma unroll
  for (int db = 0; db < 2; ++db)
    #pragma unroll
    for (int rq = 0; rq < 4; ++rq) {
      const int d0 = db * 32 + 8 * rq + 4 * hi;
      ushort4 o;
      o.x = f2bf(oacc[db][rq * 4 + 0] * rl);
      o.y = f2bf(oacc[db][rq * 4 + 1] * rl);
      o.z = f2bf(oacc[db][rq * 4 + 2] * rl);
      o.w = f2bf(oacc[db][rq * 4 + 3] * rl);
      *reinterpret_cast<ushort4*>(vals + qrowOut + d0) = o;
    }
}

// ---------------------------------------------------------------------------
extern "C" void kernel_launch(void* const* d_in, const int* in_sizes, int n_in,
                              void* d_out, int out_size, void* d_ws, size_t ws_size,
                              hipStream_t stream) {
  (void)in_sizes; (void)n_in; (void)out_size; (void)ws_size;
  const float* inputs = (const float*)d_in[0];
  const float* Wq = (const float*)d_in[1];  const float* bq = (const float*)d_in[2];
  const float* Wk = (const float*)d_in[3];  const float* bk = (const float*)d_in[4];
  const float* Wv = (const float*)d_in[5];  const float* bv = (const float*)d_in[6];
  const float* Wo = (const float*)d_in[7];  const float* bo = (const float*)d_in[8];
  const float* W1 = (const float*)d_in[9];  const float* b1 = (const float*)d_in[10];
  const float* W2 = (const float*)d_in[11]; const float* b2 = (const float*)d_in[12];
  const float* ln_g = (const float*)d_in[13];
  const float* ln_b = (const float*)d_in[14];
  const float* scale_p = (const float*)d_in[15];
  float* xbuf = (float*)d_out;               // fp32 residual stream lives here

  char* w = (char*)d_ws;
  size_t off = 0;
  auto take = [&](size_t bytes) {
    void* p = w + off;
    off = (off + bytes + 255) & ~(size_t)255;
    return p;
  };
  unsigned short* Wqkv_t = (unsigned short*)take((size_t)3072 * 1024 * 2);
  unsigned short* Wo_t   = (unsigned short*)take((size_t)1024 * 1024 * 2);
  unsigned short* W1_t   = (unsigned short*)take((size_t)4096 * 1024 * 2);
  unsigned short* W2_t   = (unsigned short*)take((size_t)1024 * 4096 * 2);
  float*          bqkv   = (float*)take(3072 * 4);
  unsigned short* rbuf   = (unsigned short*)take((size_t)4096 * 1024 * 2);
  unsigned short* qkvb   = (unsigned short*)take((size_t)4096 * 3072 * 2);
  unsigned short* vTb    = (unsigned short*)take((size_t)64 * 64 * 1024 * 2);
  unsigned short* valsb  = (unsigned short*)take((size_t)4096 * 1024 * 2);
  unsigned short* hbuf   = (unsigned short*)take((size_t)4096 * 4096 * 2);

  for (int i = 0; i < 8; ++i) {
    const float* xin = (i == 0) ? inputs : xbuf;
    // weights -> bf16, transposed [N][K]
    transpose_cvt4<<<dim3(32, 32, 4), 256, 0, stream>>>(
        Wq + (size_t)i * 1024 * 1024, Wk + (size_t)i * 1024 * 1024,
        Wv + (size_t)i * 1024 * 1024, Wo + (size_t)i * 1024 * 1024, Wqkv_t, Wo_t);
    transpose_cvt<<<dim3(32, 128), 256, 0, stream>>>(W1 + (size_t)i * 1024 * 4096, W1_t, 4096, 1024);
    transpose_cvt<<<dim3(128, 32), 256, 0, stream>>>(W2 + (size_t)i * 4096 * 1024, W2_t, 1024, 4096);
    pack_qkv_bias<<<12, 256, 0, stream>>>(bq + i * 1024, bk + i * 1024, bv + i * 1024, bqkv);
    // attention block
    ln_kernel<0><<<1024, 256, 0, stream>>>(xin, ln_g, ln_b, rbuf);
    gemm8r<3><<<192, 512, 0, stream>>>(rbuf, Wqkv_t, bqkv, qkvb, vTb, 3072, 1024);
    attn_kernel<<<512, 256, 0, stream>>>(qkvb, vTb, valsb);
    gemm4k<2><<<dim3(32, 16), 256, 0, stream>>>(valsb, Wo_t, bo + i * 1024, nullptr,
                                                xin, xbuf, scale_p, 1024, 1024);
    // FFN block
    ln_kernel<0><<<1024, 256, 0, stream>>>(xbuf, ln_g, ln_b, rbuf);
    gemm8r<1><<<256, 512, 0, stream>>>(rbuf, W1_t, b1 + i * 4096, hbuf, nullptr, 4096, 1024);
    gemm4k<2><<<dim3(32, 16), 256, 0, stream>>>(hbuf, W2_t, b2 + i * 1024, nullptr,
                                                xbuf, xbuf, scale_p, 1024, 4096);
  }
  ln_kernel<1><<<1024, 256, 0, stream>>>(xbuf, ln_g, ln_b, xbuf);  // final LN, in-place
}

// Round 16
// 1755.081 us; speedup vs baseline: 1.1966x; 1.0303x over previous
//
#include <hip/hip_runtime.h>

// ---------------------------------------------------------------------------
// Transformer decoder fwd, bf16-MFMA compute, fp32 residual stream in d_out.
// L=8 B=4 S=1024 D=1024 H=16 dh=64 FC=4096. Threshold 0.1 allows bf16 GEMMs.
// QKV/W1: 256^2 ring GEMM (BK=32, 8-slot ring, stage t+3, counted vmcnt(8)).
// Wo/W2: gemm4k (128x64, 3+3-slot ring, vmcnt(6)). LN: wave/row.
// Attn: v9 (LDS-staged K/V, 32x32 MFMA, swapped QK^T/PV, per-lane softmax).
// Weight prep: ONE kernel/layer (all transposes 32x32-tiled + bias pack).
// ---------------------------------------------------------------------------

typedef __bf16 bf16x8 __attribute__((ext_vector_type(8)));
typedef float  f32x4  __attribute__((ext_vector_type(4)));
typedef float  f32x16 __attribute__((ext_vector_type(16)));
typedef unsigned int u32x4 __attribute__((ext_vector_type(4)));

#define DEV static __device__ __forceinline__

DEV unsigned short f2bf(float x) {
  unsigned u = __builtin_bit_cast(unsigned int, x);
  u += 0x7fffu + ((u >> 16) & 1u);          // RNE
  return (unsigned short)(u >> 16);
}

DEV unsigned int pack2bf(float lo, float hi) {
  return (unsigned int)f2bf(lo) | ((unsigned int)f2bf(hi) << 16);
}

DEV f32x4 mfma16(bf16x8 a, bf16x8 b, f32x4 c) {
  return __builtin_amdgcn_mfma_f32_16x16x32_bf16(a, b, c, 0, 0, 0);
}

DEV f32x16 mfma32(bf16x8 a, bf16x8 b, f32x16 c) {
  return __builtin_amdgcn_mfma_f32_32x32x16_bf16(a, b, c, 0, 0, 0);
}

DEV bf16x8 ldb8(const unsigned short* p) {
  return *reinterpret_cast<const bf16x8*>(p);
}

DEV void gload_lds16(const unsigned short* g, unsigned short* l) {
  __builtin_amdgcn_global_load_lds(
      (const __attribute__((address_space(1))) void*)g,
      (__attribute__((address_space(3))) void*)l, 16, 0, 0);
}

// ---------------------------------------------------------------------------
// prep_layer: ALL weight prep for one layer in one dispatch.
// blocks 0..4095:      4 DxD transposes (z = bid>>10), 32x32 tiles
// blocks 4096..8191:   W1 [1024][4096] -> W1_t [4096][1024]
// blocks 8192..12287:  W2 [4096][1024] -> W2_t [1024][4096]
// blocks 12288..12299: qkv bias pack (3072 floats)
// ---------------------------------------------------------------------------
__global__ __launch_bounds__(256) void prep_layer(
    const float* __restrict__ Wq, const float* __restrict__ Wk,
    const float* __restrict__ Wv, const float* __restrict__ Wo,
    const float* __restrict__ W1, const float* __restrict__ W2,
    const float* __restrict__ bq, const float* __restrict__ bk,
    const float* __restrict__ bv,
    unsigned short* __restrict__ Wqkv_t, unsigned short* __restrict__ Wo_t,
    unsigned short* __restrict__ W1_t, unsigned short* __restrict__ W2_t,
    float* __restrict__ bqkv) {
  const int bid = blockIdx.x;
  const int t = threadIdx.x;
  if (bid >= 12288) {                        // bias pack (12 x 256 = 3072)
    const int i = (bid - 12288) * 256 + t;
    bqkv[i] = (i < 1024) ? bq[i] : (i < 2048 ? bk[i - 1024] : bv[i - 2048]);
    return;
  }
  const float* src;
  unsigned short* dst;
  int kt, nt, srcStride, dstStride;
  if (bid < 4096) {
    const int z = bid >> 10, tile = bid & 1023;
    src = (z == 0) ? Wq : (z == 1) ? Wk : (z == 2) ? Wv : Wo;
    dst = (z == 3) ? Wo_t : (Wqkv_t + (size_t)z * 1024 * 1024);
    kt = tile >> 5; nt = tile & 31; srcStride = 1024; dstStride = 1024;
  } else if (bid < 8192) {
    const int tile = bid - 4096;
    src = W1; dst = W1_t;
    kt = tile >> 7; nt = tile & 127; srcStride = 4096; dstStride = 1024;
  } else {
    const int tile = bid - 8192;
    src = W2; dst = W2_t;
    kt = tile >> 5; nt = tile & 31; srcStride = 1024; dstStride = 4096;
  }
  __shared__ float ts[32][33];
  const int r = t >> 3, c4 = (t & 7) << 2;
  const int k = kt * 32 + r, n0 = nt * 32 + c4;
  const float4 v = *reinterpret_cast<const float4*>(src + (size_t)k * srcStride + n0);
  ts[r][c4] = v.x; ts[r][c4 + 1] = v.y; ts[r][c4 + 2] = v.z; ts[r][c4 + 3] = v.w;
  __syncthreads();
  const int n = nt * 32 + r, k0 = kt * 32 + c4;
  ushort4 o;
  o.x = f2bf(ts[c4][r]);     o.y = f2bf(ts[c4 + 1][r]);
  o.z = f2bf(ts[c4 + 2][r]); o.w = f2bf(ts[c4 + 3][r]);
  *reinterpret_cast<ushort4*>(dst + (size_t)n * dstStride + k0) = o;
}

// ---------------------------------------------------------------------------
// LayerNorm v2: ONE WAVE PER ROW, 4 rows/block, grid = 1024.
// ---------------------------------------------------------------------------
template <int OUTF32>
__global__ __launch_bounds__(256) void ln_kernel(
    const float* x, const float* __restrict__ gam,
    const float* __restrict__ bet, void* out) {
  const int t = threadIdx.x, wave = t >> 6, lane = t & 63;
  const int row = blockIdx.x * 4 + wave;
  const float* xr = x + (size_t)row * 1024;
  float4 v[4];
  float s = 0.f, ss = 0.f;
  #pragma unroll
  for (int k = 0; k < 4; ++k) {
    v[k] = *reinterpret_cast<const float4*>(xr + k * 256 + lane * 4);
    s  += v[k].x + v[k].y + v[k].z + v[k].w;
    ss += v[k].x * v[k].x + v[k].y * v[k].y + v[k].z * v[k].z + v[k].w * v[k].w;
  }
  #pragma unroll
  for (int m = 1; m <= 32; m <<= 1) { s += __shfl_xor(s, m); ss += __shfl_xor(ss, m); }
  const float mean = s * (1.0f / 1024.0f);
  const float var  = ss * (1.0f / 1024.0f) - mean * mean;
  const float rstd = rsqrtf(var + 1e-5f);
  #pragma unroll
  for (int k = 0; k < 4; ++k) {
    const float4 g  = *reinterpret_cast<const float4*>(gam + k * 256 + lane * 4);
    const float4 bb = *reinterpret_cast<const float4*>(bet + k * 256 + lane * 4);
    const float y0 = (v[k].x - mean) * rstd * g.x + bb.x;
    const float y1 = (v[k].y - mean) * rstd * g.y + bb.y;
    const float y2 = (v[k].z - mean) * rstd * g.z + bb.z;
    const float y3 = (v[k].w - mean) * rstd * g.w + bb.w;
    if (OUTF32) {
      float4 o; o.x = y0; o.y = y1; o.z = y2; o.w = y3;
      *reinterpret_cast<float4*>((float*)out + (size_t)row * 1024 + k * 256 + lane * 4) = o;
    } else {
      ushort4 o; o.x = f2bf(y0); o.y = f2bf(y1); o.z = f2bf(y2); o.w = f2bf(y3);
      *reinterpret_cast<ushort4*>((unsigned short*)out + (size_t)row * 1024 + k * 256 + lane * 4) = o;
    }
  }
}

// ---------------------------------------------------------------------------
// gemm8r: 256x256 tile, BK=32, 512 thr = 8 waves. 8-slot ring (128KB);
// stage t+3; counted vmcnt(8); swizzle slot^=(row>>1)&3.
// MODE 1: bias+gelu. MODE 3: QKV split (V -> vT transposed).
// Ledger: slot of tile t+3 == slot of tile t-1 (mod 8), last read one
// barrier earlier -> WAR-safe. vmcnt(8) leaves t+2,t+3 in flight => t+1 done.
// ---------------------------------------------------------------------------
template <int MODE>
__global__ __launch_bounds__(512) void gemm8r(
    const unsigned short* __restrict__ A, const unsigned short* __restrict__ Bt,
    const float* __restrict__ bias, unsigned short* __restrict__ outb,
    unsigned short* __restrict__ vT, int N, int K) {
  __shared__ __attribute__((aligned(16))) unsigned short lds[8 * 8192]; // 128KB
  const int t = threadIdx.x, wave = t >> 6, lane = t & 63;
  const int wm = wave >> 2, wn = wave & 3;
  const int rl15 = lane & 15;

  const int nbn = N >> 8;
  const int qq  = gridDim.x >> 3;
  const int swz = (blockIdx.x & 7) * qq + (blockIdx.x >> 3);
  const int m0 = (swz / nbn) << 8, n0 = (swz % nbn) << 8;

  const unsigned short* aG = A  + (size_t)m0 * K;
  const unsigned short* bG = Bt + (size_t)n0 * K;

  const int srow = lane >> 2;
  const int ssl  = (((lane & 3) ^ ((srow >> 1) & 3)) << 3);   // shorts
  const int swA  = (((lane >> 4) ^ ((lane >> 1) & 3)) << 3);  // shorts

  auto stageA = [&](int slot, int kt) {
    #pragma unroll
    for (int j = 0; j < 2; ++j) {
      const int c = wave + j * 8;
      gload_lds16(aG + (size_t)(c * 16 + srow) * K + kt * 32 + ssl,
                  &lds[slot * 8192 + c * 512]);
    }
  };
  auto stageB = [&](int slot, int kt) {
    #pragma unroll
    for (int j = 0; j < 2; ++j) {
      const int c = wave + j * 8;
      gload_lds16(bG + (size_t)(c * 16 + srow) * K + kt * 32 + ssl,
                  &lds[slot * 8192 + c * 512]);
    }
  };

  const int nk = K >> 5;
  stageA(0, 0); stageB(1, 0);
  stageA(2, 1); stageB(3, 1);
  stageA(4, 2); stageB(5, 2);
  asm volatile("s_waitcnt vmcnt(8)" ::: "memory");   // tile 0 landed
  asm volatile("s_barrier" ::: "memory");

  f32x4 acc[8][4] = {};

  for (int kt = 0; kt < nk; ++kt) {
    if (kt + 3 < nk) {
      const int p = (2 * (kt + 3)) & 7;
      stageA(p, kt + 3); stageB(p + 1, kt + 3);
    }
    const int ab = ((2 * kt) & 7) * 8192, bb = ab + 8192;
    bf16x8 af[8], bfr[4];
    #pragma unroll
    for (int mi = 0; mi < 8; ++mi)
      af[mi] = ldb8(&lds[ab + (wm * 128 + mi * 16 + rl15) * 32 + swA]);
    #pragma unroll
    for (int ni = 0; ni < 4; ++ni)
      bfr[ni] = ldb8(&lds[bb + (wn * 64 + ni * 16 + rl15) * 32 + swA]);
    __builtin_amdgcn_s_setprio(1);
    #pragma unroll
    for (int mi = 0; mi < 8; ++mi)
      #pragma unroll
      for (int ni = 0; ni < 4; ++ni)
        acc[mi][ni] = mfma16(af[mi], bfr[ni], acc[mi][ni]);
    __builtin_amdgcn_s_setprio(0);
    if (kt + 3 < nk)      asm volatile("s_waitcnt vmcnt(8)" ::: "memory");
    else if (kt + 2 < nk) asm volatile("s_waitcnt vmcnt(4)" ::: "memory");
    else                  asm volatile("s_waitcnt vmcnt(0)" ::: "memory");
    asm volatile("s_barrier" ::: "memory");
  }

  const int mrow = m0 + wm * 128 + (lane >> 4) * 4;
  const int ncol = n0 + wn * 64 + rl15;
  #pragma unroll
  for (int ni = 0; ni < 4; ++ni) {
    const int n = ncol + ni * 16;
    const float bn = bias[n];
    #pragma unroll
    for (int mi = 0; mi < 8; ++mi) {
      const int row0 = mrow + mi * 16;
      if constexpr (MODE == 3) {
        if (n >= 2048) {                               // V -> vT[b,h,d,s]
          const int h = (n - 2048) >> 6, d = (n - 2048) & 63;
          const int b = row0 >> 10, s = row0 & 1023;
          ushort4 o;
          o.x = f2bf(acc[mi][ni][0] + bn); o.y = f2bf(acc[mi][ni][1] + bn);
          o.z = f2bf(acc[mi][ni][2] + bn); o.w = f2bf(acc[mi][ni][3] + bn);
          *reinterpret_cast<ushort4*>(vT + ((size_t)(b * 16 + h) * 64 + d) * 1024 + s) = o;
          continue;
        }
      }
      #pragma unroll
      for (int r = 0; r < 4; ++r) {
        const size_t idx = (size_t)(row0 + r) * N + n;
        float v = acc[mi][ni][r] + bn;
        if constexpr (MODE == 1)
          v = 0.5f * v * (1.0f + erff(v * 0.70710678118f));  // exact GELU
        outb[idx] = f2bf(v);
      }
    }
  }
}

// ---------------------------------------------------------------------------
// gemm4k: 128x64 tile, BK=64, 4 waves. 3+3-slot LDS ring (72KB), stage t+2,
// counted vmcnt(6). MODE 2: xout = xin + scl*(C+bias). grid (M/128, N/64).
// ---------------------------------------------------------------------------
template <int MODE>
__global__ __launch_bounds__(256) void gemm4k(
    const unsigned short* __restrict__ A, const unsigned short* __restrict__ Bt,
    const float* __restrict__ bias, unsigned short* __restrict__ outb,
    const float* xin, float* xout, const float* __restrict__ scale_p,
    int N, int K) {
  __shared__ __attribute__((aligned(16))) unsigned short lds[36864]; // 72KB
  const int t = threadIdx.x, wave = t >> 6, lane = t & 63;
  const int m0 = blockIdx.x * 128, n0 = blockIdx.y * 64;
  const int wm = wave >> 1, wn = wave & 1;

  int srowA[4], scolA[4];
  #pragma unroll
  for (int j = 0; j < 4; ++j) {
    const int c = j * 256 + wave * 64 + lane;
    const int r = c >> 3;
    srowA[j] = r;
    scolA[j] = ((c & 7) ^ (r & 7)) << 3;
  }
  const unsigned short* aBase = A + (size_t)m0 * K;
  const unsigned short* bBase = Bt + (size_t)n0 * K;

  const int xk0 = (((lane >> 4)    ) ^ (lane & 7)) << 3;
  const int xk1 = (((lane >> 4) | 4) ^ (lane & 7)) << 3;
  const int arow = (wm * 64 + (lane & 15)) * 64;
  const int brow = (wn * 32 + (lane & 15)) * 64;

  auto stage = [&](int slot, int kt) {
    unsigned short* lA = &lds[slot * 8192];
    unsigned short* lB = &lds[24576 + slot * 4096];
    const int ko = kt * 64;
    #pragma unroll
    for (int j = 0; j < 4; ++j)
      gload_lds16(aBase + (size_t)srowA[j] * K + ko + scolA[j],
                  lA + j * 2048 + wave * 512);
    #pragma unroll
    for (int j = 0; j < 2; ++j)
      gload_lds16(bBase + (size_t)srowA[j] * K + ko + scolA[j],
                  lB + j * 2048 + wave * 512);
  };

  f32x4 acc[4][2] = {};
  const int nk = K >> 6;

  stage(0, 0); stage(1, 1);
  asm volatile("s_waitcnt vmcnt(6)" ::: "memory");
  asm volatile("s_barrier" ::: "memory");

  int cs = 0;
  for (int kt = 0; kt < nk; ++kt) {
    const bool more = (kt + 2 < nk);
    if (more) { int ps = cs + 2; if (ps >= 3) ps -= 3; stage(ps, kt + 2); }
    const unsigned short* lA = &lds[cs * 8192];
    const unsigned short* lB = &lds[24576 + cs * 4096];
    #pragma unroll
    for (int kc = 0; kc < 2; ++kc) {
      const int xk = kc ? xk1 : xk0;
      bf16x8 a[4], b[2];
      #pragma unroll
      for (int mi = 0; mi < 4; ++mi) a[mi] = ldb8(&lA[arow + mi * 1024 + xk]);
      #pragma unroll
      for (int ni = 0; ni < 2; ++ni) b[ni] = ldb8(&lB[brow + ni * 1024 + xk]);
      __builtin_amdgcn_s_setprio(1);
      #pragma unroll
      for (int mi = 0; mi < 4; ++mi)
        #pragma unroll
        for (int ni = 0; ni < 2; ++ni)
          acc[mi][ni] = mfma16(a[mi], b[ni], acc[mi][ni]);
      __builtin_amdgcn_s_setprio(0);
    }
    if (more) asm volatile("s_waitcnt vmcnt(6)" ::: "memory");
    else      asm volatile("s_waitcnt vmcnt(0)" ::: "memory");
    asm volatile("s_barrier" ::: "memory");
    ++cs; if (cs == 3) cs = 0;
  }

  const int mrow = m0 + wm * 64 + (lane >> 4) * 4;
  const int ncol = n0 + wn * 32 + (lane & 15);
  float scl = 0.f;
  if constexpr (MODE == 2) scl = scale_p[0];
  #pragma unroll
  for (int ni = 0; ni < 2; ++ni) {
    const int n = ncol + ni * 16;
    const float bn = bias[n];
    #pragma unroll
    for (int mi = 0; mi < 4; ++mi) {
      #pragma unroll
      for (int r = 0; r < 4; ++r) {
        const size_t idx = (size_t)(mrow + mi * 16 + r) * N + n;
        float v = acc[mi][ni][r] + bn;
        if constexpr (MODE == 2) {
          xout[idx] = xin[idx] + scl * v;      // re-zero residual, fp32
        } else {
          outb[idx] = f2bf(v);
        }
      }
    }
  }
}

// ---------------------------------------------------------------------------
// Flash attention v9: LDS-staged K/V + 32x32x16 MFMA, swapped QK^T and PV.
// grid = 512 (= 8 q-blocks x 64 bh, heavy first), block = 256 (4 waves).
// ---------------------------------------------------------------------------
__global__ __launch_bounds__(256) void attn_kernel(
    const unsigned short* __restrict__ qkv, const unsigned short* __restrict__ vT,
    unsigned short* __restrict__ vals) {
  const int bh = blockIdx.x & 63;
  const int qb = 7 - (blockIdx.x >> 6);       // 7..0, heavy first
  const int b = bh >> 4, h = bh & 15;
  const int t = threadIdx.x, wave = t >> 6, lane = t & 63;
  const int l31 = lane & 31, hi = lane >> 5;
  const int q0w = qb * 128 + wave * 32;
  const int diag = q0w >> 6;                  // wave's diagonal KV64 tile
  const int nkt = qb * 2 + 2;                 // block KV64 tiles

  __shared__ __attribute__((aligned(16))) unsigned short ldsK[2][4096]; // 64x128B
  __shared__ __attribute__((aligned(16))) unsigned short ldsV[2][4096]; // 64x128B

  const unsigned short* qkvB  = qkv + (size_t)b * 1024 * 3072;
  const unsigned short* vHead = vT + (size_t)bh * 64 * 1024;

  const int c0row = t >> 3, c0ch = t & 7;
  const int c1row = (t + 256) >> 3, c1ch = t & 7;
  const int s0col = ((c0ch ^ (c0row & 7)) << 3);
  const int s1col = ((c1ch ^ (c1row & 7)) << 3);
  const int wbase = (t >> 6) * 512;

  auto stageKV = [&](int buf, int kt) {
    const int kv0 = kt * 64;
    gload_lds16(qkvB + (size_t)(kv0 + c0row) * 3072 + 1024 + h * 64 + s0col,
                &ldsK[buf][wbase]);
    gload_lds16(qkvB + (size_t)(kv0 + c1row) * 3072 + 1024 + h * 64 + s1col,
                &ldsK[buf][2048 + wbase]);
    gload_lds16(vHead + (size_t)c0row * 1024 + kv0 + s0col, &ldsV[buf][wbase]);
    gload_lds16(vHead + (size_t)c1row * 1024 + kv0 + s1col, &ldsV[buf][2048 + wbase]);
  };

  const unsigned short* qrow = qkvB + (size_t)(q0w + l31) * 3072 + h * 64 + hi * 8;
  bf16x8 qf[4];
  #pragma unroll
  for (int s = 0; s < 4; ++s) qf[s] = ldb8(qrow + 16 * s);

  f32x16 oacc[2] = {};
  float mrun = -1e30f, lrun = 0.f;

  stageKV(0, 0);
  __syncthreads();

  for (int kt = 0; kt < nkt; ++kt) {
    const int cur = kt & 1;
    if (kt + 1 < nkt) stageKV(cur ^ 1, kt + 1);
    if (kt <= diag) {
      const unsigned short* K = ldsK[cur];
      const unsigned short* V = ldsV[cur];
      #pragma unroll
      for (int sub = 0; sub < 2; ++sub) {
        const int krow = sub * 32 + l31;
        f32x16 sacc = {};
        #pragma unroll
        for (int s = 0; s < 4; ++s) {
          const bf16x8 kf = ldb8(&K[krow * 64 + (((2 * s + hi) ^ (krow & 7)) << 3)]);
          sacc = mfma32(kf, qf[s], sacc);
        }
        float p[16];
        #pragma unroll
        for (int r = 0; r < 16; ++r) p[r] = sacc[r] * 0.125f;
        if (kt == diag) {
          const int qg = q0w + l31;
          #pragma unroll
          for (int r = 0; r < 16; ++r) {
            const int kv = kt * 64 + sub * 32 + (r & 3) + 8 * (r >> 2) + 4 * hi;
            if (kv > qg) p[r] = -1e30f;
          }
        }
        float mloc = p[0];
        #pragma unroll
        for (int r = 1; r < 16; ++r) mloc = fmaxf(mloc, p[r]);
        mloc = fmaxf(mloc, __shfl_xor(mloc, 32));
        const float mnew = fmaxf(mrun, mloc);
        const float facq = __expf(mrun - mnew);
        mrun = mnew;
        float sloc = 0.f;
        #pragma unroll
        for (int r = 0; r < 16; ++r) {
          const float e = __expf(p[r] - mnew);
          p[r] = e;
          sloc += e;
        }
        sloc += __shfl_xor(sloc, 32);
        lrun = lrun * facq + sloc;
        #pragma unroll
        for (int db = 0; db < 2; ++db)
          #pragma unroll
          for (int r = 0; r < 16; ++r) oacc[db][r] *= facq;
        unsigned int w[8], x[8];
        #pragma unroll
        for (int i = 0; i < 8; ++i) w[i] = pack2bf(p[2 * i], p[2 * i + 1]);
        #pragma unroll
        for (int i = 0; i < 8; ++i) x[i] = (unsigned)__shfl_xor((int)w[i], 32);
        #pragma unroll
        for (int ks = 0; ks < 2; ++ks) {
          const int qi = 2 * ks + hi;
          u32x4 fu;
          if (hi) { fu = u32x4{x[2 * qi], x[2 * qi + 1], w[2 * qi], w[2 * qi + 1]}; }
          else    { fu = u32x4{w[2 * qi], w[2 * qi + 1], x[2 * qi], x[2 * qi + 1]}; }
          const bf16x8 pf = __builtin_bit_cast(bf16x8, fu);
          #pragma unroll
          for (int db = 0; db < 2; ++db) {
            const int vrow = db * 32 + l31;
            const int vch  = sub * 4 + ks * 2 + hi;
            const bf16x8 vf = ldb8(&V[vrow * 64 + ((vch ^ (vrow & 7)) << 3)]);
            oacc[db] = mfma32(vf, pf, oacc[db]);
          }
        }
      }
    }
    __syncthreads();
  }

  const float rl = 1.0f / lrun;
  const size_t qrowOut = (size_t)(b * 1024 + q0w + l31) * 1024 + h * 64;
  #pragma unroll
  for (int db = 0; db < 2; ++db)
    #pragma unroll
    for (int rq = 0; rq < 4; ++rq) {
      const int d0 = db * 32 + 8 * rq + 4 * hi;
      ushort4 o;
      o.x = f2bf(oacc[db][rq * 4 + 0] * rl);
      o.y = f2bf(oacc[db][rq * 4 + 1] * rl);
      o.z = f2bf(oacc[db][rq * 4 + 2] * rl);
      o.w = f2bf(oacc[db][rq * 4 + 3] * rl);
      *reinterpret_cast<ushort4*>(vals + qrowOut + d0) = o;
    }
}

// ---------------------------------------------------------------------------
extern "C" void kernel_launch(void* const* d_in, const int* in_sizes, int n_in,
                              void* d_out, int out_size, void* d_ws, size_t ws_size,
                              hipStream_t stream) {
  (void)in_sizes; (void)n_in; (void)out_size; (void)ws_size;
  const float* inputs = (const float*)d_in[0];
  const float* Wq = (const float*)d_in[1];  const float* bq = (const float*)d_in[2];
  const float* Wk = (const float*)d_in[3];  const float* bk = (const float*)d_in[4];
  const float* Wv = (const float*)d_in[5];  const float* bv = (const float*)d_in[6];
  const float* Wo = (const float*)d_in[7];  const float* bo = (const float*)d_in[8];
  const float* W1 = (const float*)d_in[9];  const float* b1 = (const float*)d_in[10];
  const float* W2 = (const float*)d_in[11]; const float* b2 = (const float*)d_in[12];
  const float* ln_g = (const float*)d_in[13];
  const float* ln_b = (const float*)d_in[14];
  const float* scale_p = (const float*)d_in[15];
  float* xbuf = (float*)d_out;               // fp32 residual stream lives here

  char* w = (char*)d_ws;
  size_t off = 0;
  auto take = [&](size_t bytes) {
    void* p = w + off;
    off = (off + bytes + 255) & ~(size_t)255;
    return p;
  };
  unsigned short* Wqkv_t = (unsigned short*)take((size_t)3072 * 1024 * 2);
  unsigned short* Wo_t   = (unsigned short*)take((size_t)1024 * 1024 * 2);
  unsigned short* W1_t   = (unsigned short*)take((size_t)4096 * 1024 * 2);
  unsigned short* W2_t   = (unsigned short*)take((size_t)1024 * 4096 * 2);
  float*          bqkv   = (float*)take(3072 * 4);
  unsigned short* rbuf   = (unsigned short*)take((size_t)4096 * 1024 * 2);
  unsigned short* qkvb   = (unsigned short*)take((size_t)4096 * 3072 * 2);
  unsigned short* vTb    = (unsigned short*)take((size_t)64 * 64 * 1024 * 2);
  unsigned short* valsb  = (unsigned short*)take((size_t)4096 * 1024 * 2);
  unsigned short* hbuf   = (unsigned short*)take((size_t)4096 * 4096 * 2);

  for (int i = 0; i < 8; ++i) {
    const float* xin = (i == 0) ? inputs : xbuf;
    // weights -> bf16, transposed [N][K]; qkv bias pack -- ONE dispatch
    prep_layer<<<12300, 256, 0, stream>>>(
        Wq + (size_t)i * 1024 * 1024, Wk + (size_t)i * 1024 * 1024,
        Wv + (size_t)i * 1024 * 1024, Wo + (size_t)i * 1024 * 1024,
        W1 + (size_t)i * 1024 * 4096, W2 + (size_t)i * 4096 * 1024,
        bq + i * 1024, bk + i * 1024, bv + i * 1024,
        Wqkv_t, Wo_t, W1_t, W2_t, bqkv);
    // attention block
    ln_kernel<0><<<1024, 256, 0, stream>>>(xin, ln_g, ln_b, rbuf);
    gemm8r<3><<<192, 512, 0, stream>>>(rbuf, Wqkv_t, bqkv, qkvb, vTb, 3072, 1024);
    attn_kernel<<<512, 256, 0, stream>>>(qkvb, vTb, valsb);
    gemm4k<2><<<dim3(32, 16), 256, 0, stream>>>(valsb, Wo_t, bo + i * 1024, nullptr,
                                                xin, xbuf, scale_p, 1024, 1024);
    // FFN block
    ln_kernel<0><<<1024, 256, 0, stream>>>(xbuf, ln_g, ln_b, rbuf);
    gemm8r<1><<<256, 512, 0, stream>>>(rbuf, W1_t, b1 + i * 4096, hbuf, nullptr, 4096, 1024);
    gemm4k<2><<<dim3(32, 16), 256, 0, stream>>>(hbuf, W2_t, b2 + i * 1024, nullptr,
                                                xbuf, xbuf, scale_p, 1024, 4096);
  }
  ln_kernel<1><<<1024, 256, 0, stream>>>(xbuf, ln_g, ln_b, xbuf);  // final LN, in-place
}